// Round 17
// baseline (395.406 us; speedup 1.0000x reference)
//
#include <hip/hip_runtime.h>

// ---------------- problem constants ----------------
#define NN      50000      // nodes
#define NE      500000     // edges (before self loops)
#define NET     550000     // edges + self loops
#define IND     256        // input dim
#define HC      512        // heads*hidden
#define NH      4          // heads
#define NG      512        // graphs
#define NCLS    10

typedef __attribute__((ext_vector_type(8))) _Float16 f16x8;
typedef __attribute__((ext_vector_type(4))) float f32x4;
typedef __attribute__((ext_vector_type(2))) float f32x2;
typedef __attribute__((ext_vector_type(4))) ushort us4;

// ---------------- scalar convert helpers ----------------
__device__ __forceinline__ ushort f2bf(float x) {      // fp32 -> bf16 (RNE)
    unsigned u = __float_as_uint(x);
    u += 0x7fffu + ((u >> 16) & 1u);
    return (ushort)(u >> 16);
}
__device__ __forceinline__ float bf2f(ushort h) {
    return __uint_as_float((unsigned)h << 16);
}
__device__ __forceinline__ ushort f2h(float x) {       // fp32 -> fp16 bits (RNE)
    union { _Float16 h; ushort u; } cv;
    cv.h = (_Float16)x;
    return cv.u;
}
__device__ __forceinline__ float h2f(ushort u) {       // fp16 bits -> fp32
    union { ushort u; _Float16 h; } cv;
    cv.u = u;
    return (float)cv.h;
}

// async global->LDS, 16B per lane. dst must be wave-uniform base (+lane*16 by HW).
__device__ __forceinline__ void gload_lds16(const void* g, void* s) {
    __builtin_amdgcn_global_load_lds(
        (const __attribute__((address_space(1))) unsigned*)g,
        (__attribute__((address_space(3))) unsigned*)s, 16, 0, 0);
}

// ---------------- fp16 MFMA GEMM + fused attention coefficients ----------
// zf8[M,512] = fp8_e4m3(A[M,K] @ B[K,512]);  as/ad[row,head] from fp32 acc
// (exact, pre-quantization).
// BM=64, BN=128, BK=32, DOUBLE-BUFFERED: LDS 2x12KB = 24KB -> still
// 6 blocks/CU (the r11-proven occupancy), but stage(t+1) now overlaps
// compute(t) instead of a dead drain at step head. r13's dbuf failure was
// the 48KB->3blk occupancy loss, not the schedule; this keeps both.
// Swizzle: 4 16B-chunks/row, XOR row&3 (16 lanes -> 8 banks = 2/bank, free).
__global__ __launch_bounds__(256) void k_gemm_f16(
    const ushort* __restrict__ A, const ushort* __restrict__ BT,
    const float* __restrict__ a_srcv, const float* __restrict__ a_dstv,
    unsigned char* __restrict__ Cf8, float* __restrict__ as_b,
    float* __restrict__ ad_b, int M, int K)
{
    __shared__ __align__(16) ushort As[2][64 * 32];     // 2 x 4 KB
    __shared__ __align__(16) ushort Bs[2][128 * 32];    // 2 x 8 KB
    __shared__ float sred[2][64];                       // 0.5 KB

    const int tid = threadIdx.x;
    const int nwg = gridDim.x;                       // 3128, divisible by 8
    const int orig = blockIdx.x;
    const int q = nwg >> 3, r = nwg & 7, xcd = orig & 7;
    const int wgid = (xcd < r ? xcd * (q + 1) : r * (q + 1) + (xcd - r) * q) + (orig >> 3);
    const int bm = (wgid >> 2) * 64;
    const int bn = (wgid & 3) * 128;

    const int l = tid & 63;
    const int w = tid >> 6;
    const int wm = (w >> 1) * 32, wn = (w & 1) * 64;
    const int fr = l & 15;
    const int kb = l >> 4;                   // 16B chunk index in 32-col row

    if (tid < 64) { sred[0][tid] = 0.f; sred[1][tid] = 0.f; }

    f32x4 zero = {0.f, 0.f, 0.f, 0.f};
    f32x4 acc[2][4];
#pragma unroll
    for (int m = 0; m < 2; ++m)
#pragma unroll
        for (int n = 0; n < 4; ++n) acc[m][n] = zero;

    const int nsteps = K >> 5;
    const int wbase = (tid & 0xC0) << 4;       // wave-uniform byte base

    auto stage = [&](int buf, int ks) {
        int k0 = ks << 5;
        // A tile 64x32 (4 KB): 1 chunk/thread
        {
            int row = tid >> 2;
            int col16 = (tid & 3) ^ (row & 3);
            int arow = bm + row; arow = arow < M ? arow : M - 1;
            gload_lds16(A + (size_t)arow * K + k0 + (col16 << 3),
                        (char*)As[buf] + wbase);
        }
        // B tile 128x32 (8 KB): 2 chunks/thread
#pragma unroll
        for (int i = 0; i < 2; ++i) {
            int c = i * 256 + tid;
            int j = c >> 2;
            int col16 = (c & 3) ^ (j & 3);
            gload_lds16(BT + (size_t)(bn + j) * K + k0 + (col16 << 3),
                        (char*)Bs[buf] + i * 4096 + wbase);
        }
    };

    stage(0, 0);
    __syncthreads();

    for (int ks = 0; ks < nsteps; ++ks) {
        const int cur = ks & 1;
        if (ks + 1 < nsteps) stage(cur ^ 1, ks + 1);   // prefetch next tile
        // compute current tile (prefetch latency hides under this)
        f16x8 a[2], b[4];
#pragma unroll
        for (int m = 0; m < 2; ++m) {
            int row = wm + m * 16 + fr;
            a[m] = *(const f16x8*)((const char*)As[cur] + row * 64 + ((kb ^ (row & 3)) << 4));
        }
#pragma unroll
        for (int n = 0; n < 4; ++n) {
            int col = wn + n * 16 + fr;
            b[n] = *(const f16x8*)((const char*)Bs[cur] + col * 64 + ((kb ^ (col & 3)) << 4));
        }
#pragma unroll
        for (int m = 0; m < 2; ++m)
#pragma unroll
            for (int n = 0; n < 4; ++n)
                acc[m][n] = __builtin_amdgcn_mfma_f32_16x16x32_f16(a[m], b[n], acc[m][n], 0, 0, 0);
        __syncthreads();   // drains prefetch vmcnt + guards buffer reuse
    }

    // ---- epilogue: fp8 z mirror + fused as/ad (from exact fp32 acc) ----
    const int hh = bn >> 7;                    // this block's head
    float asl[4], adl[4];
#pragma unroll
    for (int n = 0; n < 4; ++n) {
        int c = wn + n * 16 + fr;
        asl[n] = a_srcv[hh * 128 + c];
        adl[n] = a_dstv[hh * 128 + c];
    }
    const int rbase = (l >> 4) * 4;
#pragma unroll
    for (int m = 0; m < 2; ++m) {
#pragma unroll
        for (int rr = 0; rr < 4; ++rr) {
            int rloc = wm + m * 16 + rbase + rr;
            int rowi = bm + rloc;
            float ps = 0.f, pd = 0.f;
#pragma unroll
            for (int n = 0; n < 4; ++n) {
                float v = acc[m][n][rr];
                ps += v * asl[n];
                pd += v * adl[n];
                if (rowi < M) {
                    int pk = __builtin_amdgcn_cvt_pk_fp8_f32(v, v, 0, false);
                    Cf8[(size_t)rowi * HC + bn + wn + n * 16 + fr] = (unsigned char)pk;
                }
            }
#pragma unroll
            for (int off = 1; off < 16; off <<= 1) {
                ps += __shfl_xor(ps, off, 64);
                pd += __shfl_xor(pd, off, 64);
            }
            if (fr == 0) {
                atomicAdd(&sred[0][rloc], ps);
                atomicAdd(&sred[1][rloc], pd);
            }
        }
    }
    __syncthreads();
    if (tid < 64) {
        int rowi = bm + tid;
        if (rowi < M) {
            as_b[rowi * 4 + hh] = sred[0][tid];
            ad_b[rowi * 4 + hh] = sred[1][tid];
        }
    }
}

// ---------------- fused conversions (x->fp16, W1->W1T fp16, W2->W2T fp16) --
#define CVT_X4   (NN * IND / 4)          // 3,200,000 float4 chunks
#define CVT_W1   (HC * IND)              // 131,072
#define CVT_W2   (HC * HC)               // 262,144
__global__ void k_cvt_all(const float* __restrict__ x, ushort* __restrict__ xf16,
                          const float* __restrict__ W1, ushort* __restrict__ W1T,
                          const float* __restrict__ W2, ushort* __restrict__ W2T) {
    int i = blockIdx.x * blockDim.x + threadIdx.x;
    if (i < CVT_X4) {
        float4 v = ((const float4*)x)[i];
        ushort4 h;
        h.x = f2h(v.x); h.y = f2h(v.y); h.z = f2h(v.z); h.w = f2h(v.w);
        ((ushort4*)xf16)[i] = h;
        return;
    }
    i -= CVT_X4;
    if (i < CVT_W1) {                    // W1[K=256][512] -> W1T[512][256]
        int nn = i >> 8, k = i & 255;
        W1T[i] = f2h(W1[(size_t)k * HC + nn]);
        return;
    }
    i -= CVT_W1;
    if (i < CVT_W2) {                    // W2[K=512][512] -> W2T[512][512]
        int nn = i >> 9, k = i & 511;
        W2T[i] = f2h(W2[(size_t)k * HC + nn]);
    }
}

// ---------------- fused degree + graph count ----------------
__global__ void k_count(const int* __restrict__ ei, int* __restrict__ deg,
                        const int* __restrict__ batch, int* __restrict__ gcnt) {
    int i = blockIdx.x * blockDim.x + threadIdx.x;
    if (i < NET) {
        int d = (i < NE) ? ei[NE + i] : (i - NE);
        atomicAdd(&deg[d], 1);
    } else {
        int j = i - NET;
        if (j < NN) atomicAdd(&gcnt[batch[j]], 1);
    }
}

// ---- hierarchical exclusive scan (nodes: 3 kernels) ----
__global__ __launch_bounds__(256) void k_scan_part(const int* __restrict__ cnt,
                                                   int* __restrict__ bsum, int n) {
    __shared__ int red[256];
    const int tid = threadIdx.x;
    int i = blockIdx.x * 256 + tid;
    red[tid] = (i < n) ? cnt[i] : 0;
    __syncthreads();
#pragma unroll
    for (int d = 128; d; d >>= 1) {
        if (tid < d) red[tid] += red[tid + d];
        __syncthreads();
    }
    if (tid == 0) bsum[blockIdx.x] = red[0];
}

__global__ __launch_bounds__(1024) void k_scan_top(const int* __restrict__ bsum,
                                                   int* __restrict__ boff,
                                                   int* __restrict__ off, int nb, int n) {
    __shared__ int s[1024];
    const int tid = threadIdx.x;
    int v = (tid < nb) ? bsum[tid] : 0;
    s[tid] = v;
    __syncthreads();
    for (int d = 1; d < 1024; d <<= 1) {
        int t = (tid >= d) ? s[tid - d] : 0;
        __syncthreads();
        s[tid] += t;
        __syncthreads();
    }
    if (tid < nb) boff[tid] = s[tid] - v;
    if (tid == nb - 1) off[n] = s[tid];
}

__global__ __launch_bounds__(256) void k_scan_out(const int* __restrict__ cnt,
                                                  const int* __restrict__ boff,
                                                  int* __restrict__ off, int n) {
    __shared__ int s[256];
    const int tid = threadIdx.x;
    int i = blockIdx.x * 256 + tid;
    int v = (i < n) ? cnt[i] : 0;
    s[tid] = v;
    __syncthreads();
    for (int d = 1; d < 256; d <<= 1) {
        int t = (tid >= d) ? s[tid - d] : 0;
        __syncthreads();
        s[tid] += t;
        __syncthreads();
    }
    if (i < n) off[i] = boff[blockIdx.x] + s[tid] - v;
}

// single-block scan for graphs (n <= 512)
__global__ __launch_bounds__(512) void k_scan_small(const int* __restrict__ cnt,
                                                    int* __restrict__ off, int n) {
    __shared__ int s[512];
    const int tid = threadIdx.x;
    int v = (tid < n) ? cnt[tid] : 0;
    s[tid] = v;
    __syncthreads();
    for (int d = 1; d < 512; d <<= 1) {
        int t = (tid >= d) ? s[tid - d] : 0;
        __syncthreads();
        s[tid] += t;
        __syncthreads();
    }
    if (tid < n) off[tid] = s[tid] - v;
    if (tid == n - 1) off[n] = s[tid];
}

// colsrc as ushort: NN = 50000 < 65536
__global__ void k_fill(const int* __restrict__ ei,
                       const int* __restrict__ rowptr,
                       int* __restrict__ fillcnt,
                       ushort* __restrict__ colsrc) {
    int e = blockIdx.x * blockDim.x + threadIdx.x;
    if (e >= NET) return;
    int s, d;
    if (e < NE) { s = ei[e]; d = ei[NE + e]; } else { s = d = e - NE; }
    int pos = rowptr[d] + atomicAdd(&fillcnt[d], 1);
    colsrc[pos] = (ushort)s;
}

// ---------------- alpha + inverse-denominator precompute ----------------
// (r16 post-mortem: alpha TABLE beats inline recompute in the gather --
// 2B/edge streamed read < random as-load + 6 VALU on the fetch-bound path.)
__global__ __launch_bounds__(256) void k_stats(
    const float* __restrict__ as, const float* __restrict__ ad,
    const int* __restrict__ rowptr, const ushort* __restrict__ colsrc,
    ushort* __restrict__ alpha, float* __restrict__ dinv, int N)
{
    const int n = blockIdx.x * 64 + (threadIdx.x >> 2);
    if (n >= N) return;
    const int h = threadIdx.x & 3;
    const int beg = rowptr[n], end = rowptr[n + 1];
    const float adn = ad[n * 4 + h];
    float sum = 0.f;
    for (int e = beg; e < end; ++e) {
        float ev = as[(int)colsrc[e] * 4 + h] + adn;
        ev = ev > 0.f ? ev : 0.2f * ev;
        float a = __expf(ev);
        alpha[(size_t)e * 4 + h] = f2h(a);
        sum += a;
    }
    dinv[n * 4 + h] = 1.0f / (sum + 1e-16f);
}

// ---------------- fp8 weighted gather ----------------
__global__ __launch_bounds__(256) void k_gather(
    const unsigned char* __restrict__ zf8, const ushort* __restrict__ alpha,
    const float* __restrict__ dinv, const int* __restrict__ rowptr,
    const ushort* __restrict__ colsrc, const float* __restrict__ bias,
    ushort* __restrict__ o16, int obf16)
{
    const int npb = NN >> 2;                   // 12500 blocks per phase
    const int hp = blockIdx.x / npb;           // head-pair phase (0,1)
    const int sub = threadIdx.x >> 5;
    const int node = (blockIdx.x % npb) * 4 + (sub >> 1);
    const int head = hp * 2 + (sub & 1);
    const int lane = threadIdx.x & 31;
    const int beg = rowptr[node], end = rowptr[node + 1];
    const unsigned char* __restrict__ zh = zf8 + head * 128 + (lane << 2);

    float ax = 0.f, ay = 0.f, az = 0.f, aw = 0.f;
    int e = beg;
    for (; e + 8 <= end; e += 8) {
        int s[8];
        float a[8];
        unsigned u[8];
#pragma unroll
        for (int j = 0; j < 8; ++j) {
            s[j] = colsrc[e + j];
            a[j] = h2f(alpha[(size_t)(e + j) * 4 + head]);
        }
#pragma unroll
        for (int j = 0; j < 8; ++j) u[j] = *(const unsigned*)&zh[(size_t)s[j] * HC];
#pragma unroll
        for (int j = 0; j < 8; ++j) {
            f32x2 lo = __builtin_amdgcn_cvt_pk_f32_fp8(u[j], false);
            f32x2 hi = __builtin_amdgcn_cvt_pk_f32_fp8(u[j], true);
            ax += a[j] * lo.x; ay += a[j] * lo.y;
            az += a[j] * hi.x; aw += a[j] * hi.y;
        }
    }
    for (; e + 2 <= end; e += 2) {
        int s0 = colsrc[e], s1 = colsrc[e + 1];
        float a0 = h2f(alpha[(size_t)e * 4 + head]);
        float a1 = h2f(alpha[(size_t)(e + 1) * 4 + head]);
        unsigned u0 = *(const unsigned*)&zh[(size_t)s0 * HC];
        unsigned u1 = *(const unsigned*)&zh[(size_t)s1 * HC];
        f32x2 l0 = __builtin_amdgcn_cvt_pk_f32_fp8(u0, false);
        f32x2 h0 = __builtin_amdgcn_cvt_pk_f32_fp8(u0, true);
        f32x2 l1 = __builtin_amdgcn_cvt_pk_f32_fp8(u1, false);
        f32x2 h1 = __builtin_amdgcn_cvt_pk_f32_fp8(u1, true);
        ax += a0 * l0.x + a1 * l1.x; ay += a0 * l0.y + a1 * l1.y;
        az += a0 * h0.x + a1 * h1.x; aw += a0 * h0.y + a1 * h1.y;
    }
    if (e < end) {
        int s0 = colsrc[e];
        float a0 = h2f(alpha[(size_t)e * 4 + head]);
        unsigned u0 = *(const unsigned*)&zh[(size_t)s0 * HC];
        f32x2 l0 = __builtin_amdgcn_cvt_pk_f32_fp8(u0, false);
        f32x2 h0 = __builtin_amdgcn_cvt_pk_f32_fp8(u0, true);
        ax += a0 * l0.x; ay += a0 * l0.y; az += a0 * h0.x; aw += a0 * h0.y;
    }
    const float di = dinv[node * 4 + head];
    const int col = head * 128 + (lane << 2);
    float4 bv = *(const float4*)&bias[col];
    float rx = fmaxf(ax * di + bv.x, 0.f), ry = fmaxf(ay * di + bv.y, 0.f);
    float rz = fmaxf(az * di + bv.z, 0.f), rw = fmaxf(aw * di + bv.w, 0.f);
    us4 h;
    if (obf16) {
        h.x = f2bf(rx); h.y = f2bf(ry); h.z = f2bf(rz); h.w = f2bf(rw);
    } else {
        h.x = f2h(rx); h.y = f2h(ry); h.z = f2h(rz); h.w = f2h(rw);
    }
    __builtin_nontemporal_store(h, (us4*)&o16[(size_t)node * HC + col]);
}

// ---------------- pooling (bf16 input) / classifier ----------------
__global__ __launch_bounds__(128) void k_pool(const ushort* __restrict__ h,
                                              const int* __restrict__ goff,
                                              float* __restrict__ hg) {
    const int g = blockIdx.x;
    const int tid = threadIdx.x;
    const int beg = goff[g];
    const int cnt = goff[g + 1] - beg;
    float4 acc = make_float4(0.f, 0.f, 0.f, 0.f);
    for (int r = beg; r < beg + cnt; ++r) {
        ushort4 v = *(const ushort4*)&h[(size_t)r * HC + (tid << 2)];
        acc.x += bf2f(v.x); acc.y += bf2f(v.y);
        acc.z += bf2f(v.z); acc.w += bf2f(v.w);
    }
    float inv = 1.0f / (float)max(cnt, 1);
    *(float4*)&hg[(size_t)g * HC + (tid << 2)] =
        make_float4(acc.x * inv, acc.y * inv, acc.z * inv, acc.w * inv);
}

__global__ __launch_bounds__(64) void k_cls(const float* __restrict__ hg,
                                            const float* __restrict__ Wc,
                                            const float* __restrict__ bc,
                                            float* __restrict__ out) {
    const int g = blockIdx.x;
    const int lane = threadIdx.x;
#pragma unroll 1
    for (int cls = 0; cls < NCLS; ++cls) {
        float p = 0.f;
#pragma unroll
        for (int j = 0; j < 8; ++j) {
            int c = lane + j * 64;
            p += hg[(size_t)g * HC + c] * Wc[c * NCLS + cls];
        }
#pragma unroll
        for (int off = 32; off; off >>= 1) p += __shfl_down(p, off, 64);
        if (lane == 0) out[g * NCLS + cls] = p + bc[cls];
    }
}

// ---------------- launch ----------------
extern "C" void kernel_launch(void* const* d_in, const int* in_sizes, int n_in,
                              void* d_out, int out_size, void* d_ws, size_t ws_size,
                              hipStream_t stream) {
    const float* x     = (const float*)d_in[0];
    const int*   ei    = (const int*)d_in[1];
    const int*   batch = (const int*)d_in[2];
    const float* W1    = (const float*)d_in[3];
    const float* asrc1 = (const float*)d_in[4];
    const float* adst1 = (const float*)d_in[5];
    const float* b1    = (const float*)d_in[6];
    const float* W2    = (const float*)d_in[7];
    const float* asrc2 = (const float*)d_in[8];
    const float* adst2 = (const float*)d_in[9];
    const float* b2    = (const float*)d_in[10];
    const float* Wc    = (const float*)d_in[11];
    const float* bc    = (const float*)d_in[12];
    float* out = (float*)d_out;
    (void)in_sizes; (void)n_in; (void)out_size; (void)ws_size;

    // ---- region plan (sequential lifetimes on stream):
    // A @0      (25.6 MB): zf8 (fp8 z mirror, both layers)
    // B @25.6M  (51.2 MB): xf16 25.6 [cvt..GEMM1] -> h1f16 51.2 [gather1..GEMM2]
    //                      -> h2b 51.2 [gather2..pool]
    char* R = (char*)d_ws;
    const size_t MB512 = (size_t)NN * HC;        // 25.6M elements
    unsigned char* zf8 = (unsigned char*)R;
    ushort* xf16  = (ushort*)(R + MB512);
    ushort* h1f16 = (ushort*)(R + MB512);
    ushort* h2b   = (ushort*)(R + MB512);

    char* w = R + MB512 * 3;
    size_t off = 0;
    auto alloc = [&](size_t bytes) {
        void* p = w + off;
        off += (bytes + 255) & ~(size_t)255;
        return p;
    };
    float* as_b = (float*)alloc((size_t)NN * NH * 4);
    float* ad_b = (float*)alloc((size_t)NN * NH * 4);
    float* dinv = (float*)alloc((size_t)NN * NH * 4);
    int* rowptr = (int*)alloc((size_t)(NN + 1) * 4);
    int* deg    = (int*)alloc((size_t)NN * 4);
    ushort* colsrc = (ushort*)alloc((size_t)NET * 2);
    int* gcnt   = (int*)alloc((size_t)NG * 4);
    int* goff   = (int*)alloc((size_t)(NG + 1) * 4);
    int* bsum   = (int*)alloc((size_t)1024 * 4);
    int* boff   = (int*)alloc((size_t)1024 * 4);
    float* hg   = (float*)alloc((size_t)NG * HC * 4);
    ushort* W1T = (ushort*)alloc((size_t)HC * IND * 2);
    ushort* W2T = (ushort*)alloc((size_t)HC * HC * 2);
    ushort* alpha = (ushort*)alloc((size_t)NET * NH * 2);  // fp16, edge-major

    const int EB = 256, EG = (NET + EB - 1) / EB;
    const int MT = (NN + 63) / 64;               // 782 M-tiles (BM=64)
    const int GG = 2 * (NN >> 2);                // 2 head-pair phases
    const int NB_N = (NN + 255) / 256;
    const int CVT_TOTAL = CVT_X4 + CVT_W1 + CVT_W2;

    // ---- conversions (single fused kernel) ----
    k_cvt_all<<<(CVT_TOTAL + 255) / 256, 256, 0, stream>>>(x, xf16, W1, W1T, W2, W2T);

    // ---- counts (fused deg + gcnt) ----
    hipMemsetAsync(deg, 0, (size_t)NN * 4, stream);
    hipMemsetAsync(gcnt, 0, (size_t)NG * 4, stream);
    k_count<<<(NET + NN + 255) / 256, 256, 0, stream>>>(ei, deg, batch, gcnt);

    // ---- CSR rowptr (hierarchical scan) + graph offsets (1-block scan) ----
    k_scan_part<<<NB_N, 256, 0, stream>>>(deg, bsum, NN);
    k_scan_top<<<1, 1024, 0, stream>>>(bsum, boff, rowptr, NB_N, NN);
    k_scan_out<<<NB_N, 256, 0, stream>>>(deg, boff, rowptr, NN);
    k_scan_small<<<1, 512, 0, stream>>>(gcnt, goff, NG);
    hipMemsetAsync(deg, 0, (size_t)NN * 4, stream);      // reuse as fillcnt
    k_fill<<<EG, EB, 0, stream>>>(ei, rowptr, deg, colsrc);

    // ================= layer 1 =================
    k_gemm_f16<<<MT * 4, 256, 0, stream>>>(xf16, W1T, asrc1, adst1,
                                           zf8, as_b, ad_b, NN, IND);
    k_stats<<<(NN + 63) / 64, 256, 0, stream>>>(as_b, ad_b, rowptr, colsrc,
                                                alpha, dinv, NN);
    k_gather<<<GG, 256, 0, stream>>>(zf8, alpha, dinv, rowptr, colsrc, b1,
                                     h1f16, 0);

    // ================= layer 2 =================
    k_gemm_f16<<<MT * 4, 256, 0, stream>>>(h1f16, W2T, asrc2, adst2,
                                           zf8, as_b, ad_b, NN, HC);
    k_stats<<<(NN + 63) / 64, 256, 0, stream>>>(as_b, ad_b, rowptr, colsrc,
                                                alpha, dinv, NN);
    k_gather<<<GG, 256, 0, stream>>>(zf8, alpha, dinv, rowptr, colsrc, b2,
                                     h2b, 1);

    // ================= pool + classify =================
    k_pool<<<NG, 128, 0, stream>>>(h2b, goff, hg);
    k_cls<<<NG, 64, 0, stream>>>(hg, Wc, bc, out);
}

// Round 18
// 384.364 us; speedup vs baseline: 1.0287x; 1.0287x over previous
//
#include <hip/hip_runtime.h>

// ---------------- problem constants ----------------
#define NN      50000      // nodes
#define NE      500000     // edges (before self loops)
#define NET     550000     // edges + self loops
#define IND     256        // input dim
#define HC      512        // heads*hidden
#define NH      4          // heads
#define NG      512        // graphs
#define NCLS    10

typedef __attribute__((ext_vector_type(8))) _Float16 f16x8;
typedef __attribute__((ext_vector_type(4))) float f32x4;
typedef __attribute__((ext_vector_type(2))) float f32x2;
typedef __attribute__((ext_vector_type(4))) ushort us4;

// ---------------- scalar convert helpers ----------------
__device__ __forceinline__ ushort f2bf(float x) {      // fp32 -> bf16 (RNE)
    unsigned u = __float_as_uint(x);
    u += 0x7fffu + ((u >> 16) & 1u);
    return (ushort)(u >> 16);
}
__device__ __forceinline__ float bf2f(ushort h) {
    return __uint_as_float((unsigned)h << 16);
}
__device__ __forceinline__ ushort f2h(float x) {       // fp32 -> fp16 bits (RNE)
    union { _Float16 h; ushort u; } cv;
    cv.h = (_Float16)x;
    return cv.u;
}
__device__ __forceinline__ float h2f(ushort u) {       // fp16 bits -> fp32
    union { ushort u; _Float16 h; } cv;
    cv.u = u;
    return (float)cv.h;
}

// async global->LDS, 16B per lane. dst must be wave-uniform base (+lane*16 by HW).
__device__ __forceinline__ void gload_lds16(const void* g, void* s) {
    __builtin_amdgcn_global_load_lds(
        (const __attribute__((address_space(1))) unsigned*)g,
        (__attribute__((address_space(3))) unsigned*)s, 16, 0, 0);
}

// ---------------- fp16 MFMA GEMM + fused attention coefficients ----------
// zf8[M,512] = fp8_e4m3(A[M,K] @ B[K,512]);  as/ad[row,head] from fp32 acc
// (exact, pre-quantization).
// BM=64, BN=128, BK=64; 256 thr = 4 waves (2x2 of 32x64); LDS 24.5 KB ->
// 6 blocks/CU. EMPIRICAL OPTIMUM of 5 bracketing variants:
//   dbuf-BK64@3blk=75us, BM32@7blk=75us, dbuf-BK32@6blk=70us (+4.8M LDS
//   conflicts), BM128@4blk=72us, THIS=61us. Single-buffered, 16x16x32 f16.
__global__ __launch_bounds__(256) void k_gemm_f16(
    const ushort* __restrict__ A, const ushort* __restrict__ BT,
    const float* __restrict__ a_srcv, const float* __restrict__ a_dstv,
    unsigned char* __restrict__ Cf8, float* __restrict__ as_b,
    float* __restrict__ ad_b, int M, int K)
{
    __shared__ __align__(16) ushort As[64 * 64];     // 8 KB
    __shared__ __align__(16) ushort Bs[128 * 64];    // 16 KB
    __shared__ float sred[2][64];                    // 0.5 KB

    const int tid = threadIdx.x;
    const int nwg = gridDim.x;                       // 3128, divisible by 8
    const int orig = blockIdx.x;
    const int q = nwg >> 3, r = nwg & 7, xcd = orig & 7;
    const int wgid = (xcd < r ? xcd * (q + 1) : r * (q + 1) + (xcd - r) * q) + (orig >> 3);
    const int bm = (wgid >> 2) * 64;
    const int bn = (wgid & 3) * 128;

    const int l = tid & 63;
    const int w = tid >> 6;
    const int wm = (w >> 1) * 32, wn = (w & 1) * 64;
    const int fr = l & 15;
    const int fk = (l >> 4) * 8;

    if (tid < 64) { sred[0][tid] = 0.f; sred[1][tid] = 0.f; }

    f32x4 zero = {0.f, 0.f, 0.f, 0.f};
    f32x4 acc[2][4];
#pragma unroll
    for (int m = 0; m < 2; ++m)
#pragma unroll
        for (int n = 0; n < 4; ++n) acc[m][n] = zero;

    const int nsteps = K >> 6;
    const int wbase = (tid & 0xC0) << 4;       // wave-uniform byte base

    for (int ks = 0; ks < nsteps; ++ks) {
        int k0 = ks << 6;
#pragma unroll
        for (int i = 0; i < 2; ++i) {
            int c = i * 256 + tid;
            int row = c >> 3;
            int col16 = (c & 7) ^ (row & 7);
            int arow = bm + row; arow = arow < M ? arow : M - 1;
            gload_lds16(A + (size_t)arow * K + k0 + (col16 << 3),
                        (char*)As + i * 4096 + wbase);
        }
#pragma unroll
        for (int i = 0; i < 4; ++i) {
            int c = i * 256 + tid;
            int j = c >> 3;
            int col16 = (c & 7) ^ (j & 7);
            gload_lds16(BT + (size_t)(bn + j) * K + k0 + (col16 << 3),
                        (char*)Bs + i * 4096 + wbase);
        }
        __syncthreads();
#pragma unroll
        for (int kk = 0; kk < 64; kk += 32) {
            f16x8 a[2], b[4];
            int kb = (kk + fk) >> 3;
#pragma unroll
            for (int m = 0; m < 2; ++m) {
                int row = wm + m * 16 + fr;
                a[m] = *(const f16x8*)((const char*)As + row * 128 + ((kb ^ (row & 7)) << 4));
            }
#pragma unroll
            for (int n = 0; n < 4; ++n) {
                int col = wn + n * 16 + fr;
                b[n] = *(const f16x8*)((const char*)Bs + col * 128 + ((kb ^ (col & 7)) << 4));
            }
#pragma unroll
            for (int m = 0; m < 2; ++m)
#pragma unroll
                for (int n = 0; n < 4; ++n)
                    acc[m][n] = __builtin_amdgcn_mfma_f32_16x16x32_f16(a[m], b[n], acc[m][n], 0, 0, 0);
        }
        __syncthreads();
    }

    // ---- epilogue: fp8 z mirror + fused as/ad (from exact fp32 acc) ----
    const int hh = bn >> 7;                    // this block's head
    float asl[4], adl[4];
#pragma unroll
    for (int n = 0; n < 4; ++n) {
        int c = wn + n * 16 + fr;
        asl[n] = a_srcv[hh * 128 + c];
        adl[n] = a_dstv[hh * 128 + c];
    }
    const int rbase = (l >> 4) * 4;
#pragma unroll
    for (int m = 0; m < 2; ++m) {
#pragma unroll
        for (int rr = 0; rr < 4; ++rr) {
            int rloc = wm + m * 16 + rbase + rr;
            int rowi = bm + rloc;
            float ps = 0.f, pd = 0.f;
#pragma unroll
            for (int n = 0; n < 4; ++n) {
                float v = acc[m][n][rr];
                ps += v * asl[n];
                pd += v * adl[n];
                if (rowi < M) {
                    int pk = __builtin_amdgcn_cvt_pk_fp8_f32(v, v, 0, false);
                    Cf8[(size_t)rowi * HC + bn + wn + n * 16 + fr] = (unsigned char)pk;
                }
            }
#pragma unroll
            for (int off = 1; off < 16; off <<= 1) {
                ps += __shfl_xor(ps, off, 64);
                pd += __shfl_xor(pd, off, 64);
            }
            if (fr == 0) {
                atomicAdd(&sred[0][rloc], ps);
                atomicAdd(&sred[1][rloc], pd);
            }
        }
    }
    __syncthreads();
    if (tid < 64) {
        int rowi = bm + tid;
        if (rowi < M) {
            as_b[rowi * 4 + hh] = sred[0][tid];
            ad_b[rowi * 4 + hh] = sred[1][tid];
        }
    }
}

// ---------------- fused conversions (x->fp16, W1->W1T fp16, W2->W2T fp16) --
#define CVT_X4   (NN * IND / 4)          // 3,200,000 float4 chunks
#define CVT_W1   (HC * IND)              // 131,072
#define CVT_W2   (HC * HC)               // 262,144
__global__ void k_cvt_all(const float* __restrict__ x, ushort* __restrict__ xf16,
                          const float* __restrict__ W1, ushort* __restrict__ W1T,
                          const float* __restrict__ W2, ushort* __restrict__ W2T) {
    int i = blockIdx.x * blockDim.x + threadIdx.x;
    if (i < CVT_X4) {
        float4 v = ((const float4*)x)[i];
        ushort4 h;
        h.x = f2h(v.x); h.y = f2h(v.y); h.z = f2h(v.z); h.w = f2h(v.w);
        ((ushort4*)xf16)[i] = h;
        return;
    }
    i -= CVT_X4;
    if (i < CVT_W1) {                    // W1[K=256][512] -> W1T[512][256]
        int nn = i >> 8, k = i & 255;
        W1T[i] = f2h(W1[(size_t)k * HC + nn]);
        return;
    }
    i -= CVT_W1;
    if (i < CVT_W2) {                    // W2[K=512][512] -> W2T[512][512]
        int nn = i >> 9, k = i & 511;
        W2T[i] = f2h(W2[(size_t)k * HC + nn]);
    }
}

// ---------------- fused degree + graph count ----------------
__global__ void k_count(const int* __restrict__ ei, int* __restrict__ deg,
                        const int* __restrict__ batch, int* __restrict__ gcnt) {
    int i = blockIdx.x * blockDim.x + threadIdx.x;
    if (i < NET) {
        int d = (i < NE) ? ei[NE + i] : (i - NE);
        atomicAdd(&deg[d], 1);
    } else {
        int j = i - NET;
        if (j < NN) atomicAdd(&gcnt[batch[j]], 1);
    }
}

// ---- hierarchical exclusive scan (nodes: 3 kernels) ----
__global__ __launch_bounds__(256) void k_scan_part(const int* __restrict__ cnt,
                                                   int* __restrict__ bsum, int n) {
    __shared__ int red[256];
    const int tid = threadIdx.x;
    int i = blockIdx.x * 256 + tid;
    red[tid] = (i < n) ? cnt[i] : 0;
    __syncthreads();
#pragma unroll
    for (int d = 128; d; d >>= 1) {
        if (tid < d) red[tid] += red[tid + d];
        __syncthreads();
    }
    if (tid == 0) bsum[blockIdx.x] = red[0];
}

__global__ __launch_bounds__(1024) void k_scan_top(const int* __restrict__ bsum,
                                                   int* __restrict__ boff,
                                                   int* __restrict__ off, int nb, int n) {
    __shared__ int s[1024];
    const int tid = threadIdx.x;
    int v = (tid < nb) ? bsum[tid] : 0;
    s[tid] = v;
    __syncthreads();
    for (int d = 1; d < 1024; d <<= 1) {
        int t = (tid >= d) ? s[tid - d] : 0;
        __syncthreads();
        s[tid] += t;
        __syncthreads();
    }
    if (tid < nb) boff[tid] = s[tid] - v;
    if (tid == nb - 1) off[n] = s[tid];
}

__global__ __launch_bounds__(256) void k_scan_out(const int* __restrict__ cnt,
                                                  const int* __restrict__ boff,
                                                  int* __restrict__ off, int n) {
    __shared__ int s[256];
    const int tid = threadIdx.x;
    int i = blockIdx.x * 256 + tid;
    int v = (i < n) ? cnt[i] : 0;
    s[tid] = v;
    __syncthreads();
    for (int d = 1; d < 256; d <<= 1) {
        int t = (tid >= d) ? s[tid - d] : 0;
        __syncthreads();
        s[tid] += t;
        __syncthreads();
    }
    if (i < n) off[i] = boff[blockIdx.x] + s[tid] - v;
}

// single-block scan for graphs (n <= 512)
__global__ __launch_bounds__(512) void k_scan_small(const int* __restrict__ cnt,
                                                    int* __restrict__ off, int n) {
    __shared__ int s[512];
    const int tid = threadIdx.x;
    int v = (tid < n) ? cnt[tid] : 0;
    s[tid] = v;
    __syncthreads();
    for (int d = 1; d < 512; d <<= 1) {
        int t = (tid >= d) ? s[tid - d] : 0;
        __syncthreads();
        s[tid] += t;
        __syncthreads();
    }
    if (tid < n) off[tid] = s[tid] - v;
    if (tid == n - 1) off[n] = s[tid];
}

// colsrc as ushort: NN = 50000 < 65536
__global__ void k_fill(const int* __restrict__ ei,
                       const int* __restrict__ rowptr,
                       int* __restrict__ fillcnt,
                       ushort* __restrict__ colsrc) {
    int e = blockIdx.x * blockDim.x + threadIdx.x;
    if (e >= NET) return;
    int s, d;
    if (e < NE) { s = ei[e]; d = ei[NE + e]; } else { s = d = e - NE; }
    int pos = rowptr[d] + atomicAdd(&fillcnt[d], 1);
    colsrc[pos] = (ushort)s;
}

// ---------------- alpha + inverse-denominator precompute ----------------
// (r16 post-mortem: alpha TABLE beats inline recompute in the gather --
// 2B/edge streamed read < random as-load + 6 VALU on the fetch-bound path.)
__global__ __launch_bounds__(256) void k_stats(
    const float* __restrict__ as, const float* __restrict__ ad,
    const int* __restrict__ rowptr, const ushort* __restrict__ colsrc,
    ushort* __restrict__ alpha, float* __restrict__ dinv, int N)
{
    const int n = blockIdx.x * 64 + (threadIdx.x >> 2);
    if (n >= N) return;
    const int h = threadIdx.x & 3;
    const int beg = rowptr[n], end = rowptr[n + 1];
    const float adn = ad[n * 4 + h];
    float sum = 0.f;
    for (int e = beg; e < end; ++e) {
        float ev = as[(int)colsrc[e] * 4 + h] + adn;
        ev = ev > 0.f ? ev : 0.2f * ev;
        float a = __expf(ev);
        alpha[(size_t)e * 4 + h] = f2h(a);
        sum += a;
    }
    dinv[n * 4 + h] = 1.0f / (sum + 1e-16f);
}

// ---------------- fp8 weighted gather ----------------
__global__ __launch_bounds__(256) void k_gather(
    const unsigned char* __restrict__ zf8, const ushort* __restrict__ alpha,
    const float* __restrict__ dinv, const int* __restrict__ rowptr,
    const ushort* __restrict__ colsrc, const float* __restrict__ bias,
    ushort* __restrict__ o16, int obf16)
{
    const int npb = NN >> 2;                   // 12500 blocks per phase
    const int hp = blockIdx.x / npb;           // head-pair phase (0,1)
    const int sub = threadIdx.x >> 5;
    const int node = (blockIdx.x % npb) * 4 + (sub >> 1);
    const int head = hp * 2 + (sub & 1);
    const int lane = threadIdx.x & 31;
    const int beg = rowptr[node], end = rowptr[node + 1];
    const unsigned char* __restrict__ zh = zf8 + head * 128 + (lane << 2);

    float ax = 0.f, ay = 0.f, az = 0.f, aw = 0.f;
    int e = beg;
    for (; e + 8 <= end; e += 8) {
        int s[8];
        float a[8];
        unsigned u[8];
#pragma unroll
        for (int j = 0; j < 8; ++j) {
            s[j] = colsrc[e + j];
            a[j] = h2f(alpha[(size_t)(e + j) * 4 + head]);
        }
#pragma unroll
        for (int j = 0; j < 8; ++j) u[j] = *(const unsigned*)&zh[(size_t)s[j] * HC];
#pragma unroll
        for (int j = 0; j < 8; ++j) {
            f32x2 lo = __builtin_amdgcn_cvt_pk_f32_fp8(u[j], false);
            f32x2 hi = __builtin_amdgcn_cvt_pk_f32_fp8(u[j], true);
            ax += a[j] * lo.x; ay += a[j] * lo.y;
            az += a[j] * hi.x; aw += a[j] * hi.y;
        }
    }
    for (; e + 2 <= end; e += 2) {
        int s0 = colsrc[e], s1 = colsrc[e + 1];
        float a0 = h2f(alpha[(size_t)e * 4 + head]);
        float a1 = h2f(alpha[(size_t)(e + 1) * 4 + head]);
        unsigned u0 = *(const unsigned*)&zh[(size_t)s0 * HC];
        unsigned u1 = *(const unsigned*)&zh[(size_t)s1 * HC];
        f32x2 l0 = __builtin_amdgcn_cvt_pk_f32_fp8(u0, false);
        f32x2 h0 = __builtin_amdgcn_cvt_pk_f32_fp8(u0, true);
        f32x2 l1 = __builtin_amdgcn_cvt_pk_f32_fp8(u1, false);
        f32x2 h1 = __builtin_amdgcn_cvt_pk_f32_fp8(u1, true);
        ax += a0 * l0.x + a1 * l1.x; ay += a0 * l0.y + a1 * l1.y;
        az += a0 * h0.x + a1 * h1.x; aw += a0 * h0.y + a1 * h1.y;
    }
    if (e < end) {
        int s0 = colsrc[e];
        float a0 = h2f(alpha[(size_t)e * 4 + head]);
        unsigned u0 = *(const unsigned*)&zh[(size_t)s0 * HC];
        f32x2 l0 = __builtin_amdgcn_cvt_pk_f32_fp8(u0, false);
        f32x2 h0 = __builtin_amdgcn_cvt_pk_f32_fp8(u0, true);
        ax += a0 * l0.x; ay += a0 * l0.y; az += a0 * h0.x; aw += a0 * h0.y;
    }
    const float di = dinv[node * 4 + head];
    const int col = head * 128 + (lane << 2);
    float4 bv = *(const float4*)&bias[col];
    float rx = fmaxf(ax * di + bv.x, 0.f), ry = fmaxf(ay * di + bv.y, 0.f);
    float rz = fmaxf(az * di + bv.z, 0.f), rw = fmaxf(aw * di + bv.w, 0.f);
    us4 h;
    if (obf16) {
        h.x = f2bf(rx); h.y = f2bf(ry); h.z = f2bf(rz); h.w = f2bf(rw);
    } else {
        h.x = f2h(rx); h.y = f2h(ry); h.z = f2h(rz); h.w = f2h(rw);
    }
    __builtin_nontemporal_store(h, (us4*)&o16[(size_t)node * HC + col]);
}

// ---------------- pooling (bf16 input) / classifier ----------------
__global__ __launch_bounds__(128) void k_pool(const ushort* __restrict__ h,
                                              const int* __restrict__ goff,
                                              float* __restrict__ hg) {
    const int g = blockIdx.x;
    const int tid = threadIdx.x;
    const int beg = goff[g];
    const int cnt = goff[g + 1] - beg;
    float4 acc = make_float4(0.f, 0.f, 0.f, 0.f);
    for (int r = beg; r < beg + cnt; ++r) {
        ushort4 v = *(const ushort4*)&h[(size_t)r * HC + (tid << 2)];
        acc.x += bf2f(v.x); acc.y += bf2f(v.y);
        acc.z += bf2f(v.z); acc.w += bf2f(v.w);
    }
    float inv = 1.0f / (float)max(cnt, 1);
    *(float4*)&hg[(size_t)g * HC + (tid << 2)] =
        make_float4(acc.x * inv, acc.y * inv, acc.z * inv, acc.w * inv);
}

__global__ __launch_bounds__(64) void k_cls(const float* __restrict__ hg,
                                            const float* __restrict__ Wc,
                                            const float* __restrict__ bc,
                                            float* __restrict__ out) {
    const int g = blockIdx.x;
    const int lane = threadIdx.x;
#pragma unroll 1
    for (int cls = 0; cls < NCLS; ++cls) {
        float p = 0.f;
#pragma unroll
        for (int j = 0; j < 8; ++j) {
            int c = lane + j * 64;
            p += hg[(size_t)g * HC + c] * Wc[c * NCLS + cls];
        }
#pragma unroll
        for (int off = 32; off; off >>= 1) p += __shfl_down(p, off, 64);
        if (lane == 0) out[g * NCLS + cls] = p + bc[cls];
    }
}

// ---------------- launch ----------------
extern "C" void kernel_launch(void* const* d_in, const int* in_sizes, int n_in,
                              void* d_out, int out_size, void* d_ws, size_t ws_size,
                              hipStream_t stream) {
    const float* x     = (const float*)d_in[0];
    const int*   ei    = (const int*)d_in[1];
    const int*   batch = (const int*)d_in[2];
    const float* W1    = (const float*)d_in[3];
    const float* asrc1 = (const float*)d_in[4];
    const float* adst1 = (const float*)d_in[5];
    const float* b1    = (const float*)d_in[6];
    const float* W2    = (const float*)d_in[7];
    const float* asrc2 = (const float*)d_in[8];
    const float* adst2 = (const float*)d_in[9];
    const float* b2    = (const float*)d_in[10];
    const float* Wc    = (const float*)d_in[11];
    const float* bc    = (const float*)d_in[12];
    float* out = (float*)d_out;
    (void)in_sizes; (void)n_in; (void)out_size; (void)ws_size;

    // ---- region plan (sequential lifetimes on stream):
    // A @0      (25.6 MB): zf8 (fp8 z mirror, both layers)
    // B @25.6M  (51.2 MB): xf16 25.6 [cvt..GEMM1] -> h1f16 51.2 [gather1..GEMM2]
    //                      -> h2b 51.2 [gather2..pool]
    char* R = (char*)d_ws;
    const size_t MB512 = (size_t)NN * HC;        // 25.6M elements
    unsigned char* zf8 = (unsigned char*)R;
    ushort* xf16  = (ushort*)(R + MB512);
    ushort* h1f16 = (ushort*)(R + MB512);
    ushort* h2b   = (ushort*)(R + MB512);

    char* w = R + MB512 * 3;
    size_t off = 0;
    auto alloc = [&](size_t bytes) {
        void* p = w + off;
        off += (bytes + 255) & ~(size_t)255;
        return p;
    };
    float* as_b = (float*)alloc((size_t)NN * NH * 4);
    float* ad_b = (float*)alloc((size_t)NN * NH * 4);
    float* dinv = (float*)alloc((size_t)NN * NH * 4);
    int* rowptr = (int*)alloc((size_t)(NN + 1) * 4);
    int* deg    = (int*)alloc((size_t)NN * 4);
    ushort* colsrc = (ushort*)alloc((size_t)NET * 2);
    int* gcnt   = (int*)alloc((size_t)NG * 4);
    int* goff   = (int*)alloc((size_t)(NG + 1) * 4);
    int* bsum   = (int*)alloc((size_t)1024 * 4);
    int* boff   = (int*)alloc((size_t)1024 * 4);
    float* hg   = (float*)alloc((size_t)NG * HC * 4);
    ushort* W1T = (ushort*)alloc((size_t)HC * IND * 2);
    ushort* W2T = (ushort*)alloc((size_t)HC * HC * 2);
    ushort* alpha = (ushort*)alloc((size_t)NET * NH * 2);  // fp16, edge-major

    const int EB = 256, EG = (NET + EB - 1) / EB;
    const int MT = (NN + 63) / 64;               // 782 M-tiles (BM=64)
    const int GG = 2 * (NN >> 2);                // 2 head-pair phases
    const int NB_N = (NN + 255) / 256;
    const int CVT_TOTAL = CVT_X4 + CVT_W1 + CVT_W2;

    // ---- conversions (single fused kernel) ----
    k_cvt_all<<<(CVT_TOTAL + 255) / 256, 256, 0, stream>>>(x, xf16, W1, W1T, W2, W2T);

    // ---- counts (fused deg + gcnt) ----
    hipMemsetAsync(deg, 0, (size_t)NN * 4, stream);
    hipMemsetAsync(gcnt, 0, (size_t)NG * 4, stream);
    k_count<<<(NET + NN + 255) / 256, 256, 0, stream>>>(ei, deg, batch, gcnt);

    // ---- CSR rowptr (hierarchical scan) + graph offsets (1-block scan) ----
    k_scan_part<<<NB_N, 256, 0, stream>>>(deg, bsum, NN);
    k_scan_top<<<1, 1024, 0, stream>>>(bsum, boff, rowptr, NB_N, NN);
    k_scan_out<<<NB_N, 256, 0, stream>>>(deg, boff, rowptr, NN);
    k_scan_small<<<1, 512, 0, stream>>>(gcnt, goff, NG);
    hipMemsetAsync(deg, 0, (size_t)NN * 4, stream);      // reuse as fillcnt
    k_fill<<<EG, EB, 0, stream>>>(ei, rowptr, deg, colsrc);

    // ================= layer 1 =================
    k_gemm_f16<<<MT * 4, 256, 0, stream>>>(xf16, W1T, asrc1, adst1,
                                           zf8, as_b, ad_b, NN, IND);
    k_stats<<<(NN + 63) / 64, 256, 0, stream>>>(as_b, ad_b, rowptr, colsrc,
                                                alpha, dinv, NN);
    k_gather<<<GG, 256, 0, stream>>>(zf8, alpha, dinv, rowptr, colsrc, b1,
                                     h1f16, 0);

    // ================= layer 2 =================
    k_gemm_f16<<<MT * 4, 256, 0, stream>>>(h1f16, W2T, asrc2, adst2,
                                           zf8, as_b, ad_b, NN, HC);
    k_stats<<<(NN + 63) / 64, 256, 0, stream>>>(as_b, ad_b, rowptr, colsrc,
                                                alpha, dinv, NN);
    k_gather<<<GG, 256, 0, stream>>>(zf8, alpha, dinv, rowptr, colsrc, b2,
                                     h2b, 1);

    // ================= pool + classify =================
    k_pool<<<NG, 128, 0, stream>>>(h2b, goff, hg);
    k_cls<<<NG, 64, 0, stream>>>(hg, Wc, bc, out);
}

// Round 19
// 379.286 us; speedup vs baseline: 1.0425x; 1.0134x over previous
//
#include <hip/hip_runtime.h>

// ---------------- problem constants ----------------
#define NN      50000      // nodes
#define NE      500000     // edges (before self loops)
#define NET     550000     // edges + self loops
#define IND     256        // input dim
#define HC      512        // heads*hidden
#define NH      4          // heads
#define NG      512        // graphs
#define NCLS    10

typedef __attribute__((ext_vector_type(8))) _Float16 f16x8;
typedef __attribute__((ext_vector_type(4))) float f32x4;
typedef __attribute__((ext_vector_type(2))) float f32x2;
typedef __attribute__((ext_vector_type(4))) ushort us4;

// ---------------- scalar convert helpers ----------------
__device__ __forceinline__ ushort f2bf(float x) {      // fp32 -> bf16 (RNE)
    unsigned u = __float_as_uint(x);
    u += 0x7fffu + ((u >> 16) & 1u);
    return (ushort)(u >> 16);
}
__device__ __forceinline__ float bf2f(ushort h) {
    return __uint_as_float((unsigned)h << 16);
}
__device__ __forceinline__ ushort f2h(float x) {       // fp32 -> fp16 bits (RNE)
    union { _Float16 h; ushort u; } cv;
    cv.h = (_Float16)x;
    return cv.u;
}
__device__ __forceinline__ float h2f(ushort u) {       // fp16 bits -> fp32
    union { ushort u; _Float16 h; } cv;
    cv.u = u;
    return (float)cv.h;
}

// async global->LDS, 16B per lane. dst must be wave-uniform base (+lane*16 by HW).
__device__ __forceinline__ void gload_lds16(const void* g, void* s) {
    __builtin_amdgcn_global_load_lds(
        (const __attribute__((address_space(1))) unsigned*)g,
        (__attribute__((address_space(3))) unsigned*)s, 16, 0, 0);
}

// ---------------- fp16 MFMA GEMM + fused attention coefficients ----------
// zf8[M,512] = fp8_e4m3(A[M,K] @ B[K,512]);  as/ad[row,head] from fp32 acc
// (exact, pre-quantization).
// BM=64, BN=128, BK=64; 256 thr = 4 waves (2x2 of 32x64); LDS 24.5 KB ->
// 6 blocks/CU. EMPIRICAL OPTIMUM of 5 bracketing variants:
//   dbuf-BK64@3blk=75us, BM32@7blk=75us, dbuf-BK32@6blk=70us (+4.8M LDS
//   conflicts), BM128@4blk=72us, THIS=61us. Single-buffered, 16x16x32 f16.
__global__ __launch_bounds__(256) void k_gemm_f16(
    const ushort* __restrict__ A, const ushort* __restrict__ BT,
    const float* __restrict__ a_srcv, const float* __restrict__ a_dstv,
    unsigned char* __restrict__ Cf8, float* __restrict__ as_b,
    float* __restrict__ ad_b, int M, int K)
{
    __shared__ __align__(16) ushort As[64 * 64];     // 8 KB
    __shared__ __align__(16) ushort Bs[128 * 64];    // 16 KB
    __shared__ float sred[2][64];                    // 0.5 KB

    const int tid = threadIdx.x;
    const int nwg = gridDim.x;                       // 3128, divisible by 8
    const int orig = blockIdx.x;
    const int q = nwg >> 3, r = nwg & 7, xcd = orig & 7;
    const int wgid = (xcd < r ? xcd * (q + 1) : r * (q + 1) + (xcd - r) * q) + (orig >> 3);
    const int bm = (wgid >> 2) * 64;
    const int bn = (wgid & 3) * 128;

    const int l = tid & 63;
    const int w = tid >> 6;
    const int wm = (w >> 1) * 32, wn = (w & 1) * 64;
    const int fr = l & 15;
    const int fk = (l >> 4) * 8;

    if (tid < 64) { sred[0][tid] = 0.f; sred[1][tid] = 0.f; }

    f32x4 zero = {0.f, 0.f, 0.f, 0.f};
    f32x4 acc[2][4];
#pragma unroll
    for (int m = 0; m < 2; ++m)
#pragma unroll
        for (int n = 0; n < 4; ++n) acc[m][n] = zero;

    const int nsteps = K >> 6;
    const int wbase = (tid & 0xC0) << 4;       // wave-uniform byte base

    for (int ks = 0; ks < nsteps; ++ks) {
        int k0 = ks << 6;
#pragma unroll
        for (int i = 0; i < 2; ++i) {
            int c = i * 256 + tid;
            int row = c >> 3;
            int col16 = (c & 7) ^ (row & 7);
            int arow = bm + row; arow = arow < M ? arow : M - 1;
            gload_lds16(A + (size_t)arow * K + k0 + (col16 << 3),
                        (char*)As + i * 4096 + wbase);
        }
#pragma unroll
        for (int i = 0; i < 4; ++i) {
            int c = i * 256 + tid;
            int j = c >> 3;
            int col16 = (c & 7) ^ (j & 7);
            gload_lds16(BT + (size_t)(bn + j) * K + k0 + (col16 << 3),
                        (char*)Bs + i * 4096 + wbase);
        }
        __syncthreads();
#pragma unroll
        for (int kk = 0; kk < 64; kk += 32) {
            f16x8 a[2], b[4];
            int kb = (kk + fk) >> 3;
#pragma unroll
            for (int m = 0; m < 2; ++m) {
                int row = wm + m * 16 + fr;
                a[m] = *(const f16x8*)((const char*)As + row * 128 + ((kb ^ (row & 7)) << 4));
            }
#pragma unroll
            for (int n = 0; n < 4; ++n) {
                int col = wn + n * 16 + fr;
                b[n] = *(const f16x8*)((const char*)Bs + col * 128 + ((kb ^ (col & 7)) << 4));
            }
#pragma unroll
            for (int m = 0; m < 2; ++m)
#pragma unroll
                for (int n = 0; n < 4; ++n)
                    acc[m][n] = __builtin_amdgcn_mfma_f32_16x16x32_f16(a[m], b[n], acc[m][n], 0, 0, 0);
        }
        __syncthreads();
    }

    // ---- epilogue: fp8 z mirror + fused as/ad (from exact fp32 acc) ----
    const int hh = bn >> 7;                    // this block's head
    float asl[4], adl[4];
#pragma unroll
    for (int n = 0; n < 4; ++n) {
        int c = wn + n * 16 + fr;
        asl[n] = a_srcv[hh * 128 + c];
        adl[n] = a_dstv[hh * 128 + c];
    }
    const int rbase = (l >> 4) * 4;
#pragma unroll
    for (int m = 0; m < 2; ++m) {
#pragma unroll
        for (int rr = 0; rr < 4; ++rr) {
            int rloc = wm + m * 16 + rbase + rr;
            int rowi = bm + rloc;
            float ps = 0.f, pd = 0.f;
#pragma unroll
            for (int n = 0; n < 4; ++n) {
                float v = acc[m][n][rr];
                ps += v * asl[n];
                pd += v * adl[n];
                if (rowi < M) {
                    int pk = __builtin_amdgcn_cvt_pk_fp8_f32(v, v, 0, false);
                    Cf8[(size_t)rowi * HC + bn + wn + n * 16 + fr] = (unsigned char)pk;
                }
            }
#pragma unroll
            for (int off = 1; off < 16; off <<= 1) {
                ps += __shfl_xor(ps, off, 64);
                pd += __shfl_xor(pd, off, 64);
            }
            if (fr == 0) {
                atomicAdd(&sred[0][rloc], ps);
                atomicAdd(&sred[1][rloc], pd);
            }
        }
    }
    __syncthreads();
    if (tid < 64) {
        int rowi = bm + tid;
        if (rowi < M) {
            as_b[rowi * 4 + hh] = sred[0][tid];
            ad_b[rowi * 4 + hh] = sred[1][tid];
        }
    }
}

// ------- fused prologue: conversions + zero deg/fillcnt/gcnt -------------
// (folds 3 hipMemsetAsync nodes into the cvt kernel; stream order makes the
// zeroes visible to k_count's atomics.)
#define CVT_X4   (NN * IND / 4)          // 3,200,000 float4 chunks
#define CVT_W1   (HC * IND)              // 131,072
#define CVT_W2   (HC * HC)               // 262,144
#define Z_DEG    NN
#define Z_FILL   NN
#define Z_GCNT   NG
#define CVT_TOTAL (CVT_X4 + CVT_W1 + CVT_W2 + Z_DEG + Z_FILL + Z_GCNT)
__global__ void k_cvt_all(const float* __restrict__ x, ushort* __restrict__ xf16,
                          const float* __restrict__ W1, ushort* __restrict__ W1T,
                          const float* __restrict__ W2, ushort* __restrict__ W2T,
                          int* __restrict__ deg, int* __restrict__ fillcnt,
                          int* __restrict__ gcnt) {
    int i = blockIdx.x * blockDim.x + threadIdx.x;
    if (i < CVT_X4) {
        float4 v = ((const float4*)x)[i];
        ushort4 h;
        h.x = f2h(v.x); h.y = f2h(v.y); h.z = f2h(v.z); h.w = f2h(v.w);
        ((ushort4*)xf16)[i] = h;
        return;
    }
    i -= CVT_X4;
    if (i < CVT_W1) {                    // W1[K=256][512] -> W1T[512][256]
        int nn = i >> 8, k = i & 255;
        W1T[i] = f2h(W1[(size_t)k * HC + nn]);
        return;
    }
    i -= CVT_W1;
    if (i < CVT_W2) {                    // W2[K=512][512] -> W2T[512][512]
        int nn = i >> 9, k = i & 511;
        W2T[i] = f2h(W2[(size_t)k * HC + nn]);
        return;
    }
    i -= CVT_W2;
    if (i < Z_DEG)  { deg[i] = 0; return; }
    i -= Z_DEG;
    if (i < Z_FILL) { fillcnt[i] = 0; return; }
    i -= Z_FILL;
    if (i < Z_GCNT) gcnt[i] = 0;
}

// ---------------- fused degree + graph count ----------------
__global__ void k_count(const int* __restrict__ ei, int* __restrict__ deg,
                        const int* __restrict__ batch, int* __restrict__ gcnt) {
    int i = blockIdx.x * blockDim.x + threadIdx.x;
    if (i < NET) {
        int d = (i < NE) ? ei[NE + i] : (i - NE);
        atomicAdd(&deg[d], 1);
    } else {
        int j = i - NET;
        if (j < NN) atomicAdd(&gcnt[batch[j]], 1);
    }
}

// ---- hierarchical exclusive scan ----
__global__ __launch_bounds__(256) void k_scan_part(const int* __restrict__ cnt,
                                                   int* __restrict__ bsum, int n) {
    __shared__ int red[256];
    const int tid = threadIdx.x;
    int i = blockIdx.x * 256 + tid;
    red[tid] = (i < n) ? cnt[i] : 0;
    __syncthreads();
#pragma unroll
    for (int d = 128; d; d >>= 1) {
        if (tid < d) red[tid] += red[tid + d];
        __syncthreads();
    }
    if (tid == 0) bsum[blockIdx.x] = red[0];
}

// single block: phase A scans the node block-sums; phase B scans the 512
// graph counts (merged k_scan_small -> one fewer dispatch).
__global__ __launch_bounds__(1024) void k_scan_top(const int* __restrict__ bsum,
                                                   int* __restrict__ boff,
                                                   int* __restrict__ off, int nb, int n,
                                                   const int* __restrict__ gcnt,
                                                   int* __restrict__ goff, int ng) {
    __shared__ int s[1024];
    const int tid = threadIdx.x;
    // phase A: node block sums
    int v = (tid < nb) ? bsum[tid] : 0;
    s[tid] = v;
    __syncthreads();
    for (int d = 1; d < 1024; d <<= 1) {
        int t = (tid >= d) ? s[tid - d] : 0;
        __syncthreads();
        s[tid] += t;
        __syncthreads();
    }
    if (tid < nb) boff[tid] = s[tid] - v;
    if (tid == nb - 1) off[n] = s[tid];
    __syncthreads();
    // phase B: graph counts (ng <= 1024)
    int gv = (tid < ng) ? gcnt[tid] : 0;
    s[tid] = gv;
    __syncthreads();
    for (int d = 1; d < 1024; d <<= 1) {
        int t = (tid >= d) ? s[tid - d] : 0;
        __syncthreads();
        s[tid] += t;
        __syncthreads();
    }
    if (tid < ng) goff[tid] = s[tid] - gv;
    if (tid == ng - 1) goff[ng] = s[tid];
}

__global__ __launch_bounds__(256) void k_scan_out(const int* __restrict__ cnt,
                                                  const int* __restrict__ boff,
                                                  int* __restrict__ off, int n) {
    __shared__ int s[256];
    const int tid = threadIdx.x;
    int i = blockIdx.x * 256 + tid;
    int v = (i < n) ? cnt[i] : 0;
    s[tid] = v;
    __syncthreads();
    for (int d = 1; d < 256; d <<= 1) {
        int t = (tid >= d) ? s[tid - d] : 0;
        __syncthreads();
        s[tid] += t;
        __syncthreads();
    }
    if (i < n) off[i] = boff[blockIdx.x] + s[tid] - v;
}

// colsrc as ushort: NN = 50000 < 65536
__global__ void k_fill(const int* __restrict__ ei,
                       const int* __restrict__ rowptr,
                       int* __restrict__ fillcnt,
                       ushort* __restrict__ colsrc) {
    int e = blockIdx.x * blockDim.x + threadIdx.x;
    if (e >= NET) return;
    int s, d;
    if (e < NE) { s = ei[e]; d = ei[NE + e]; } else { s = d = e - NE; }
    int pos = rowptr[d] + atomicAdd(&fillcnt[d], 1);
    colsrc[pos] = (ushort)s;
}

// ---------------- alpha + inverse-denominator precompute ----------------
// (r16: alpha TABLE beats inline recompute on the fetch-bound gather path.)
__global__ __launch_bounds__(256) void k_stats(
    const float* __restrict__ as, const float* __restrict__ ad,
    const int* __restrict__ rowptr, const ushort* __restrict__ colsrc,
    ushort* __restrict__ alpha, float* __restrict__ dinv, int N)
{
    const int n = blockIdx.x * 64 + (threadIdx.x >> 2);
    if (n >= N) return;
    const int h = threadIdx.x & 3;
    const int beg = rowptr[n], end = rowptr[n + 1];
    const float adn = ad[n * 4 + h];
    float sum = 0.f;
    for (int e = beg; e < end; ++e) {
        float ev = as[(int)colsrc[e] * 4 + h] + adn;
        ev = ev > 0.f ? ev : 0.2f * ev;
        float a = __expf(ev);
        alpha[(size_t)e * 4 + h] = f2h(a);
        sum += a;
    }
    dinv[n * 4 + h] = 1.0f / (sum + 1e-16f);
}

// ---------------- fp8 weighted gather ----------------
__global__ __launch_bounds__(256) void k_gather(
    const unsigned char* __restrict__ zf8, const ushort* __restrict__ alpha,
    const float* __restrict__ dinv, const int* __restrict__ rowptr,
    const ushort* __restrict__ colsrc, const float* __restrict__ bias,
    ushort* __restrict__ o16, int obf16)
{
    const int npb = NN >> 2;                   // 12500 blocks per phase
    const int hp = blockIdx.x / npb;           // head-pair phase (0,1)
    const int sub = threadIdx.x >> 5;
    const int node = (blockIdx.x % npb) * 4 + (sub >> 1);
    const int head = hp * 2 + (sub & 1);
    const int lane = threadIdx.x & 31;
    const int beg = rowptr[node], end = rowptr[node + 1];
    const unsigned char* __restrict__ zh = zf8 + head * 128 + (lane << 2);

    float ax = 0.f, ay = 0.f, az = 0.f, aw = 0.f;
    int e = beg;
    for (; e + 8 <= end; e += 8) {
        int s[8];
        float a[8];
        unsigned u[8];
#pragma unroll
        for (int j = 0; j < 8; ++j) {
            s[j] = colsrc[e + j];
            a[j] = h2f(alpha[(size_t)(e + j) * 4 + head]);
        }
#pragma unroll
        for (int j = 0; j < 8; ++j) u[j] = *(const unsigned*)&zh[(size_t)s[j] * HC];
#pragma unroll
        for (int j = 0; j < 8; ++j) {
            f32x2 lo = __builtin_amdgcn_cvt_pk_f32_fp8(u[j], false);
            f32x2 hi = __builtin_amdgcn_cvt_pk_f32_fp8(u[j], true);
            ax += a[j] * lo.x; ay += a[j] * lo.y;
            az += a[j] * hi.x; aw += a[j] * hi.y;
        }
    }
    for (; e + 2 <= end; e += 2) {
        int s0 = colsrc[e], s1 = colsrc[e + 1];
        float a0 = h2f(alpha[(size_t)e * 4 + head]);
        float a1 = h2f(alpha[(size_t)(e + 1) * 4 + head]);
        unsigned u0 = *(const unsigned*)&zh[(size_t)s0 * HC];
        unsigned u1 = *(const unsigned*)&zh[(size_t)s1 * HC];
        f32x2 l0 = __builtin_amdgcn_cvt_pk_f32_fp8(u0, false);
        f32x2 h0 = __builtin_amdgcn_cvt_pk_f32_fp8(u0, true);
        f32x2 l1 = __builtin_amdgcn_cvt_pk_f32_fp8(u1, false);
        f32x2 h1 = __builtin_amdgcn_cvt_pk_f32_fp8(u1, true);
        ax += a0 * l0.x + a1 * l1.x; ay += a0 * l0.y + a1 * l1.y;
        az += a0 * h0.x + a1 * h1.x; aw += a0 * h0.y + a1 * h1.y;
    }
    if (e < end) {
        int s0 = colsrc[e];
        float a0 = h2f(alpha[(size_t)e * 4 + head]);
        unsigned u0 = *(const unsigned*)&zh[(size_t)s0 * HC];
        f32x2 l0 = __builtin_amdgcn_cvt_pk_f32_fp8(u0, false);
        f32x2 h0 = __builtin_amdgcn_cvt_pk_f32_fp8(u0, true);
        ax += a0 * l0.x; ay += a0 * l0.y; az += a0 * h0.x; aw += a0 * h0.y;
    }
    const float di = dinv[node * 4 + head];
    const int col = head * 128 + (lane << 2);
    float4 bv = *(const float4*)&bias[col];
    float rx = fmaxf(ax * di + bv.x, 0.f), ry = fmaxf(ay * di + bv.y, 0.f);
    float rz = fmaxf(az * di + bv.z, 0.f), rw = fmaxf(aw * di + bv.w, 0.f);
    us4 h;
    if (obf16) {
        h.x = f2bf(rx); h.y = f2bf(ry); h.z = f2bf(rz); h.w = f2bf(rw);
    } else {
        h.x = f2h(rx); h.y = f2h(ry); h.z = f2h(rz); h.w = f2h(rw);
    }
    __builtin_nontemporal_store(h, (us4*)&o16[(size_t)node * HC + col]);
}

// ---------- fused pooling + classifier (hg row stays in LDS) ----------
__global__ __launch_bounds__(128) void k_poolcls(const ushort* __restrict__ h,
                                                 const int* __restrict__ goff,
                                                 const float* __restrict__ Wc,
                                                 const float* __restrict__ bc,
                                                 float* __restrict__ out) {
    __shared__ float shg[HC];
    const int g = blockIdx.x;
    const int tid = threadIdx.x;
    const int beg = goff[g];
    const int cnt = goff[g + 1] - beg;
    float4 acc = make_float4(0.f, 0.f, 0.f, 0.f);
    for (int r = beg; r < beg + cnt; ++r) {
        ushort4 v = *(const ushort4*)&h[(size_t)r * HC + (tid << 2)];
        acc.x += bf2f(v.x); acc.y += bf2f(v.y);
        acc.z += bf2f(v.z); acc.w += bf2f(v.w);
    }
    float inv = 1.0f / (float)max(cnt, 1);
    *(float4*)&shg[tid << 2] =
        make_float4(acc.x * inv, acc.y * inv, acc.z * inv, acc.w * inv);
    __syncthreads();
    if (tid < NCLS) {
        float p = bc[tid];
        for (int j = 0; j < HC; ++j) p += shg[j] * Wc[j * NCLS + tid];
        out[g * NCLS + tid] = p;
    }
}

// ---------------- launch ----------------
extern "C" void kernel_launch(void* const* d_in, const int* in_sizes, int n_in,
                              void* d_out, int out_size, void* d_ws, size_t ws_size,
                              hipStream_t stream) {
    const float* x     = (const float*)d_in[0];
    const int*   ei    = (const int*)d_in[1];
    const int*   batch = (const int*)d_in[2];
    const float* W1    = (const float*)d_in[3];
    const float* asrc1 = (const float*)d_in[4];
    const float* adst1 = (const float*)d_in[5];
    const float* b1    = (const float*)d_in[6];
    const float* W2    = (const float*)d_in[7];
    const float* asrc2 = (const float*)d_in[8];
    const float* adst2 = (const float*)d_in[9];
    const float* b2    = (const float*)d_in[10];
    const float* Wc    = (const float*)d_in[11];
    const float* bc    = (const float*)d_in[12];
    float* out = (float*)d_out;
    (void)in_sizes; (void)n_in; (void)out_size; (void)ws_size;

    // ---- region plan (sequential lifetimes on stream):
    // A @0      (25.6 MB): zf8 (fp8 z mirror, both layers)
    // B @25.6M  (51.2 MB): xf16 25.6 [cvt..GEMM1] -> h1f16 51.2 [gather1..GEMM2]
    //                      -> h2b 51.2 [gather2..poolcls]
    char* R = (char*)d_ws;
    const size_t MB512 = (size_t)NN * HC;        // 25.6M elements
    unsigned char* zf8 = (unsigned char*)R;
    ushort* xf16  = (ushort*)(R + MB512);
    ushort* h1f16 = (ushort*)(R + MB512);
    ushort* h2b   = (ushort*)(R + MB512);

    char* w = R + MB512 * 3;
    size_t off = 0;
    auto alloc = [&](size_t bytes) {
        void* p = w + off;
        off += (bytes + 255) & ~(size_t)255;
        return p;
    };
    float* as_b = (float*)alloc((size_t)NN * NH * 4);
    float* ad_b = (float*)alloc((size_t)NN * NH * 4);
    float* dinv = (float*)alloc((size_t)NN * NH * 4);
    int* rowptr = (int*)alloc((size_t)(NN + 1) * 4);
    int* deg    = (int*)alloc((size_t)NN * 4);
    int* fillc  = (int*)alloc((size_t)NN * 4);
    ushort* colsrc = (ushort*)alloc((size_t)NET * 2);
    int* gcnt   = (int*)alloc((size_t)NG * 4);
    int* goff   = (int*)alloc((size_t)(NG + 1) * 4);
    int* bsum   = (int*)alloc((size_t)1024 * 4);
    int* boff   = (int*)alloc((size_t)1024 * 4);
    ushort* W1T = (ushort*)alloc((size_t)HC * IND * 2);
    ushort* W2T = (ushort*)alloc((size_t)HC * HC * 2);
    ushort* alpha = (ushort*)alloc((size_t)NET * NH * 2);  // fp16, edge-major

    const int EB = 256, EG = (NET + EB - 1) / EB;
    const int MT = (NN + 63) / 64;               // 782 M-tiles (BM=64)
    const int GG = 2 * (NN >> 2);                // 2 head-pair phases
    const int NB_N = (NN + 255) / 256;

    // ---- prologue: conversions + zeroing (1 kernel, replaces 1+3 nodes) ----
    k_cvt_all<<<(CVT_TOTAL + 255) / 256, 256, 0, stream>>>(
        x, xf16, W1, W1T, W2, W2T, deg, fillc, gcnt);

    // ---- counts (fused deg + gcnt) ----
    k_count<<<(NET + NN + 255) / 256, 256, 0, stream>>>(ei, deg, batch, gcnt);

    // ---- CSR rowptr scan (+ merged graph-offset scan) ----
    k_scan_part<<<NB_N, 256, 0, stream>>>(deg, bsum, NN);
    k_scan_top<<<1, 1024, 0, stream>>>(bsum, boff, rowptr, NB_N, NN,
                                       gcnt, goff, NG);
    k_scan_out<<<NB_N, 256, 0, stream>>>(deg, boff, rowptr, NN);
    k_fill<<<EG, EB, 0, stream>>>(ei, rowptr, fillc, colsrc);

    // ================= layer 1 =================
    k_gemm_f16<<<MT * 4, 256, 0, stream>>>(xf16, W1T, asrc1, adst1,
                                           zf8, as_b, ad_b, NN, IND);
    k_stats<<<(NN + 63) / 64, 256, 0, stream>>>(as_b, ad_b, rowptr, colsrc,
                                                alpha, dinv, NN);
    k_gather<<<GG, 256, 0, stream>>>(zf8, alpha, dinv, rowptr, colsrc, b1,
                                     h1f16, 0);

    // ================= layer 2 =================
    k_gemm_f16<<<MT * 4, 256, 0, stream>>>(h1f16, W2T, asrc2, adst2,
                                           zf8, as_b, ad_b, NN, HC);
    k_stats<<<(NN + 63) / 64, 256, 0, stream>>>(as_b, ad_b, rowptr, colsrc,
                                                alpha, dinv, NN);
    k_gather<<<GG, 256, 0, stream>>>(zf8, alpha, dinv, rowptr, colsrc, b2,
                                     h2b, 1);

    // ================= pool + classify (fused) =================
    k_poolcls<<<NG, 128, 0, stream>>>(h2b, goff, Wc, bc, out);
}

// Round 20
// 343.482 us; speedup vs baseline: 1.1512x; 1.1042x over previous
//
#include <hip/hip_runtime.h>

// ---------------- problem constants ----------------
#define NN      50000      // nodes
#define NE      500000     // edges (before self loops)
#define NET     550000     // edges + self loops
#define IND     256        // input dim
#define HC      512        // heads*hidden
#define NH      4          // heads
#define NG      512        // graphs
#define NCLS    10

typedef __attribute__((ext_vector_type(8))) _Float16 f16x8;
typedef __attribute__((ext_vector_type(4))) float f32x4;
typedef __attribute__((ext_vector_type(2))) float f32x2;
typedef __attribute__((ext_vector_type(4))) ushort us4;

// ---------------- scalar convert helpers ----------------
__device__ __forceinline__ ushort f2bf(float x) {      // fp32 -> bf16 (RNE)
    unsigned u = __float_as_uint(x);
    u += 0x7fffu + ((u >> 16) & 1u);
    return (ushort)(u >> 16);
}
__device__ __forceinline__ float bf2f(ushort h) {
    return __uint_as_float((unsigned)h << 16);
}
__device__ __forceinline__ ushort f2h(float x) {       // fp32 -> fp16 bits (RNE)
    union { _Float16 h; ushort u; } cv;
    cv.h = (_Float16)x;
    return cv.u;
}
__device__ __forceinline__ float h2f(ushort u) {       // fp16 bits -> fp32
    union { ushort u; _Float16 h; } cv;
    cv.u = u;
    return (float)cv.h;
}

// async global->LDS, 16B per lane. dst must be wave-uniform base (+lane*16 by HW).
__device__ __forceinline__ void gload_lds16(const void* g, void* s) {
    __builtin_amdgcn_global_load_lds(
        (const __attribute__((address_space(1))) unsigned*)g,
        (__attribute__((address_space(3))) unsigned*)s, 16, 0, 0);
}

// ---------------- fp16 MFMA GEMM + fused attention coefficients ----------
// zf8[M,512] = fp8_e4m3(A[M,K] @ B[K,512]);  as/ad[row,head] from fp32 acc
// (exact, pre-quantization).
// BM=64, BN=128, BK=64; 256 thr = 4 waves (2x2 of 32x64); LDS 24.5 KB ->
// 6 blocks/CU. EMPIRICAL OPTIMUM of 5 bracketing variants:
//   dbuf-BK64@3blk=75us, BM32@7blk=75us, dbuf-BK32@6blk=70us (+4.8M LDS
//   conflicts), BM128@4blk=72us, THIS=61us. Single-buffered, 16x16x32 f16.
__global__ __launch_bounds__(256) void k_gemm_f16(
    const ushort* __restrict__ A, const ushort* __restrict__ BT,
    const float* __restrict__ a_srcv, const float* __restrict__ a_dstv,
    unsigned char* __restrict__ Cf8, float* __restrict__ as_b,
    float* __restrict__ ad_b, int M, int K)
{
    __shared__ __align__(16) ushort As[64 * 64];     // 8 KB
    __shared__ __align__(16) ushort Bs[128 * 64];    // 16 KB
    __shared__ float sred[2][64];                    // 0.5 KB

    const int tid = threadIdx.x;
    const int nwg = gridDim.x;                       // 3128, divisible by 8
    const int orig = blockIdx.x;
    const int q = nwg >> 3, r = nwg & 7, xcd = orig & 7;
    const int wgid = (xcd < r ? xcd * (q + 1) : r * (q + 1) + (xcd - r) * q) + (orig >> 3);
    const int bm = (wgid >> 2) * 64;
    const int bn = (wgid & 3) * 128;

    const int l = tid & 63;
    const int w = tid >> 6;
    const int wm = (w >> 1) * 32, wn = (w & 1) * 64;
    const int fr = l & 15;
    const int fk = (l >> 4) * 8;

    if (tid < 64) { sred[0][tid] = 0.f; sred[1][tid] = 0.f; }

    f32x4 zero = {0.f, 0.f, 0.f, 0.f};
    f32x4 acc[2][4];
#pragma unroll
    for (int m = 0; m < 2; ++m)
#pragma unroll
        for (int n = 0; n < 4; ++n) acc[m][n] = zero;

    const int nsteps = K >> 6;
    const int wbase = (tid & 0xC0) << 4;       // wave-uniform byte base

    for (int ks = 0; ks < nsteps; ++ks) {
        int k0 = ks << 6;
#pragma unroll
        for (int i = 0; i < 2; ++i) {
            int c = i * 256 + tid;
            int row = c >> 3;
            int col16 = (c & 7) ^ (row & 7);
            int arow = bm + row; arow = arow < M ? arow : M - 1;
            gload_lds16(A + (size_t)arow * K + k0 + (col16 << 3),
                        (char*)As + i * 4096 + wbase);
        }
#pragma unroll
        for (int i = 0; i < 4; ++i) {
            int c = i * 256 + tid;
            int j = c >> 3;
            int col16 = (c & 7) ^ (j & 7);
            gload_lds16(BT + (size_t)(bn + j) * K + k0 + (col16 << 3),
                        (char*)Bs + i * 4096 + wbase);
        }
        __syncthreads();
#pragma unroll
        for (int kk = 0; kk < 64; kk += 32) {
            f16x8 a[2], b[4];
            int kb = (kk + fk) >> 3;
#pragma unroll
            for (int m = 0; m < 2; ++m) {
                int row = wm + m * 16 + fr;
                a[m] = *(const f16x8*)((const char*)As + row * 128 + ((kb ^ (row & 7)) << 4));
            }
#pragma unroll
            for (int n = 0; n < 4; ++n) {
                int col = wn + n * 16 + fr;
                b[n] = *(const f16x8*)((const char*)Bs + col * 128 + ((kb ^ (col & 7)) << 4));
            }
#pragma unroll
            for (int m = 0; m < 2; ++m)
#pragma unroll
                for (int n = 0; n < 4; ++n)
                    acc[m][n] = __builtin_amdgcn_mfma_f32_16x16x32_f16(a[m], b[n], acc[m][n], 0, 0, 0);
        }
        __syncthreads();
    }

    // ---- epilogue: fp8 z mirror + fused as/ad (from exact fp32 acc) ----
    const int hh = bn >> 7;                    // this block's head
    float asl[4], adl[4];
#pragma unroll
    for (int n = 0; n < 4; ++n) {
        int c = wn + n * 16 + fr;
        asl[n] = a_srcv[hh * 128 + c];
        adl[n] = a_dstv[hh * 128 + c];
    }
    const int rbase = (l >> 4) * 4;
#pragma unroll
    for (int m = 0; m < 2; ++m) {
#pragma unroll
        for (int rr = 0; rr < 4; ++rr) {
            int rloc = wm + m * 16 + rbase + rr;
            int rowi = bm + rloc;
            float ps = 0.f, pd = 0.f;
#pragma unroll
            for (int n = 0; n < 4; ++n) {
                float v = acc[m][n][rr];
                ps += v * asl[n];
                pd += v * adl[n];
                if (rowi < M) {
                    int pk = __builtin_amdgcn_cvt_pk_fp8_f32(v, v, 0, false);
                    Cf8[(size_t)rowi * HC + bn + wn + n * 16 + fr] = (unsigned char)pk;
                }
            }
#pragma unroll
            for (int off = 1; off < 16; off <<= 1) {
                ps += __shfl_xor(ps, off, 64);
                pd += __shfl_xor(pd, off, 64);
            }
            if (fr == 0) {
                atomicAdd(&sred[0][rloc], ps);
                atomicAdd(&sred[1][rloc], pd);
            }
        }
    }
    __syncthreads();
    if (tid < 64) {
        int rowi = bm + tid;
        if (rowi < M) {
            as_b[rowi * 4 + hh] = sred[0][tid];
            ad_b[rowi * 4 + hh] = sred[1][tid];
        }
    }
}

// ------- fused prologue: conversions + zero deg/fillcnt/gcnt -------------
#define CVT_X4   (NN * IND / 4)          // 3,200,000 float4 chunks
#define CVT_W1   (HC * IND)              // 131,072
#define CVT_W2   (HC * HC)               // 262,144
#define Z_DEG    NN
#define Z_FILL   NN
#define Z_GCNT   NG
#define CVT_TOTAL (CVT_X4 + CVT_W1 + CVT_W2 + Z_DEG + Z_FILL + Z_GCNT)
__global__ void k_cvt_all(const float* __restrict__ x, ushort* __restrict__ xf16,
                          const float* __restrict__ W1, ushort* __restrict__ W1T,
                          const float* __restrict__ W2, ushort* __restrict__ W2T,
                          int* __restrict__ deg, int* __restrict__ fillcnt,
                          int* __restrict__ gcnt) {
    int i = blockIdx.x * blockDim.x + threadIdx.x;
    if (i < CVT_X4) {
        float4 v = ((const float4*)x)[i];
        ushort4 h;
        h.x = f2h(v.x); h.y = f2h(v.y); h.z = f2h(v.z); h.w = f2h(v.w);
        ((ushort4*)xf16)[i] = h;
        return;
    }
    i -= CVT_X4;
    if (i < CVT_W1) {                    // W1[K=256][512] -> W1T[512][256]
        int nn = i >> 8, k = i & 255;
        W1T[i] = f2h(W1[(size_t)k * HC + nn]);
        return;
    }
    i -= CVT_W1;
    if (i < CVT_W2) {                    // W2[K=512][512] -> W2T[512][512]
        int nn = i >> 9, k = i & 511;
        W2T[i] = f2h(W2[(size_t)k * HC + nn]);
        return;
    }
    i -= CVT_W2;
    if (i < Z_DEG)  { deg[i] = 0; return; }
    i -= Z_DEG;
    if (i < Z_FILL) { fillcnt[i] = 0; return; }
    i -= Z_FILL;
    if (i < Z_GCNT) gcnt[i] = 0;
}

// ---------------- fused degree + graph count ----------------
__global__ void k_count(const int* __restrict__ ei, int* __restrict__ deg,
                        const int* __restrict__ batch, int* __restrict__ gcnt) {
    int i = blockIdx.x * blockDim.x + threadIdx.x;
    if (i < NET) {
        int d = (i < NE) ? ei[NE + i] : (i - NE);
        atomicAdd(&deg[d], 1);
    } else {
        int j = i - NET;
        if (j < NN) atomicAdd(&gcnt[batch[j]], 1);
    }
}

// ---- hierarchical exclusive scan ----
__global__ __launch_bounds__(256) void k_scan_part(const int* __restrict__ cnt,
                                                   int* __restrict__ bsum, int n) {
    __shared__ int red[256];
    const int tid = threadIdx.x;
    int i = blockIdx.x * 256 + tid;
    red[tid] = (i < n) ? cnt[i] : 0;
    __syncthreads();
#pragma unroll
    for (int d = 128; d; d >>= 1) {
        if (tid < d) red[tid] += red[tid + d];
        __syncthreads();
    }
    if (tid == 0) bsum[blockIdx.x] = red[0];
}

// single block: phase A scans node block-sums; phase B scans graph counts.
__global__ __launch_bounds__(1024) void k_scan_top(const int* __restrict__ bsum,
                                                   int* __restrict__ boff,
                                                   int* __restrict__ off, int nb, int n,
                                                   const int* __restrict__ gcnt,
                                                   int* __restrict__ goff, int ng) {
    __shared__ int s[1024];
    const int tid = threadIdx.x;
    int v = (tid < nb) ? bsum[tid] : 0;
    s[tid] = v;
    __syncthreads();
    for (int d = 1; d < 1024; d <<= 1) {
        int t = (tid >= d) ? s[tid - d] : 0;
        __syncthreads();
        s[tid] += t;
        __syncthreads();
    }
    if (tid < nb) boff[tid] = s[tid] - v;
    if (tid == nb - 1) off[n] = s[tid];
    __syncthreads();
    int gv = (tid < ng) ? gcnt[tid] : 0;
    s[tid] = gv;
    __syncthreads();
    for (int d = 1; d < 1024; d <<= 1) {
        int t = (tid >= d) ? s[tid - d] : 0;
        __syncthreads();
        s[tid] += t;
        __syncthreads();
    }
    if (tid < ng) goff[tid] = s[tid] - gv;
    if (tid == ng - 1) goff[ng] = s[tid];
}

__global__ __launch_bounds__(256) void k_scan_out(const int* __restrict__ cnt,
                                                  const int* __restrict__ boff,
                                                  int* __restrict__ off, int n) {
    __shared__ int s[256];
    const int tid = threadIdx.x;
    int i = blockIdx.x * 256 + tid;
    int v = (i < n) ? cnt[i] : 0;
    s[tid] = v;
    __syncthreads();
    for (int d = 1; d < 256; d <<= 1) {
        int t = (tid >= d) ? s[tid - d] : 0;
        __syncthreads();
        s[tid] += t;
        __syncthreads();
    }
    if (i < n) off[i] = boff[blockIdx.x] + s[tid] - v;
}

// colsrc as ushort: NN = 50000 < 65536
__global__ void k_fill(const int* __restrict__ ei,
                       const int* __restrict__ rowptr,
                       int* __restrict__ fillcnt,
                       ushort* __restrict__ colsrc) {
    int e = blockIdx.x * blockDim.x + threadIdx.x;
    if (e >= NET) return;
    int s, d;
    if (e < NE) { s = ei[e]; d = ei[NE + e]; } else { s = d = e - NE; }
    int pos = rowptr[d] + atomicAdd(&fillcnt[d], 1);
    colsrc[pos] = (ushort)s;
}

// ---------------- alpha + inverse-denominator precompute ----------------
__global__ __launch_bounds__(256) void k_stats(
    const float* __restrict__ as, const float* __restrict__ ad,
    const int* __restrict__ rowptr, const ushort* __restrict__ colsrc,
    ushort* __restrict__ alpha, float* __restrict__ dinv, int N)
{
    const int n = blockIdx.x * 64 + (threadIdx.x >> 2);
    if (n >= N) return;
    const int h = threadIdx.x & 3;
    const int beg = rowptr[n], end = rowptr[n + 1];
    const float adn = ad[n * 4 + h];
    float sum = 0.f;
    for (int e = beg; e < end; ++e) {
        float ev = as[(int)colsrc[e] * 4 + h] + adn;
        ev = ev > 0.f ? ev : 0.2f * ev;
        float a = __expf(ev);
        alpha[(size_t)e * 4 + h] = f2h(a);
        sum += a;
    }
    dinv[n * 4 + h] = 1.0f / (sum + 1e-16f);
}

// ---------------- fp8 weighted gather ----------------
__global__ __launch_bounds__(256) void k_gather(
    const unsigned char* __restrict__ zf8, const ushort* __restrict__ alpha,
    const float* __restrict__ dinv, const int* __restrict__ rowptr,
    const ushort* __restrict__ colsrc, const float* __restrict__ bias,
    ushort* __restrict__ o16, int obf16)
{
    const int npb = NN >> 2;                   // 12500 blocks per phase
    const int hp = blockIdx.x / npb;           // head-pair phase (0,1)
    const int sub = threadIdx.x >> 5;
    const int node = (blockIdx.x % npb) * 4 + (sub >> 1);
    const int head = hp * 2 + (sub & 1);
    const int lane = threadIdx.x & 31;
    const int beg = rowptr[node], end = rowptr[node + 1];
    const unsigned char* __restrict__ zh = zf8 + head * 128 + (lane << 2);

    float ax = 0.f, ay = 0.f, az = 0.f, aw = 0.f;
    int e = beg;
    for (; e + 8 <= end; e += 8) {
        int s[8];
        float a[8];
        unsigned u[8];
#pragma unroll
        for (int j = 0; j < 8; ++j) {
            s[j] = colsrc[e + j];
            a[j] = h2f(alpha[(size_t)(e + j) * 4 + head]);
        }
#pragma unroll
        for (int j = 0; j < 8; ++j) u[j] = *(const unsigned*)&zh[(size_t)s[j] * HC];
#pragma unroll
        for (int j = 0; j < 8; ++j) {
            f32x2 lo = __builtin_amdgcn_cvt_pk_f32_fp8(u[j], false);
            f32x2 hi = __builtin_amdgcn_cvt_pk_f32_fp8(u[j], true);
            ax += a[j] * lo.x; ay += a[j] * lo.y;
            az += a[j] * hi.x; aw += a[j] * hi.y;
        }
    }
    for (; e + 2 <= end; e += 2) {
        int s0 = colsrc[e], s1 = colsrc[e + 1];
        float a0 = h2f(alpha[(size_t)e * 4 + head]);
        float a1 = h2f(alpha[(size_t)(e + 1) * 4 + head]);
        unsigned u0 = *(const unsigned*)&zh[(size_t)s0 * HC];
        unsigned u1 = *(const unsigned*)&zh[(size_t)s1 * HC];
        f32x2 l0 = __builtin_amdgcn_cvt_pk_f32_fp8(u0, false);
        f32x2 h0 = __builtin_amdgcn_cvt_pk_f32_fp8(u0, true);
        f32x2 l1 = __builtin_amdgcn_cvt_pk_f32_fp8(u1, false);
        f32x2 h1 = __builtin_amdgcn_cvt_pk_f32_fp8(u1, true);
        ax += a0 * l0.x + a1 * l1.x; ay += a0 * l0.y + a1 * l1.y;
        az += a0 * h0.x + a1 * h1.x; aw += a0 * h0.y + a1 * h1.y;
    }
    if (e < end) {
        int s0 = colsrc[e];
        float a0 = h2f(alpha[(size_t)e * 4 + head]);
        unsigned u0 = *(const unsigned*)&zh[(size_t)s0 * HC];
        f32x2 l0 = __builtin_amdgcn_cvt_pk_f32_fp8(u0, false);
        f32x2 h0 = __builtin_amdgcn_cvt_pk_f32_fp8(u0, true);
        ax += a0 * l0.x; ay += a0 * l0.y; az += a0 * h0.x; aw += a0 * h0.y;
    }
    const float di = dinv[node * 4 + head];
    const int col = head * 128 + (lane << 2);
    float4 bv = *(const float4*)&bias[col];
    float rx = fmaxf(ax * di + bv.x, 0.f), ry = fmaxf(ay * di + bv.y, 0.f);
    float rz = fmaxf(az * di + bv.z, 0.f), rw = fmaxf(aw * di + bv.w, 0.f);
    us4 h;
    if (obf16) {
        h.x = f2bf(rx); h.y = f2bf(ry); h.z = f2bf(rz); h.w = f2bf(rw);
    } else {
        h.x = f2h(rx); h.y = f2h(ry); h.z = f2h(rz); h.w = f2h(rw);
    }
    __builtin_nontemporal_store(h, (us4*)&o16[(size_t)node * HC + col]);
}

// ---------- fused pooling + classifier, 8-way row-parallel ----------
// r19 post-mortem: 128-thr version was latency-starved (97 serial row trips,
// occ 7.8%, 65us). 1024 thr = 8 row-groups x 128 col-threads -> ~12 trips,
// partials tree-combined in LDS, then the 10-class dot.
__global__ __launch_bounds__(1024) void k_poolcls(const ushort* __restrict__ h,
                                                  const int* __restrict__ goff,
                                                  const float* __restrict__ Wc,
                                                  const float* __restrict__ bc,
                                                  float* __restrict__ out) {
    __shared__ float shg[8][HC];                 // 16 KB
    const int g = blockIdx.x;
    const int tid = threadIdx.x;
    const int grp = tid >> 7;                    // 0..7 row group
    const int ct  = tid & 127;                   // column thread
    const int beg = goff[g];
    const int cnt = goff[g + 1] - beg;
    float4 acc = make_float4(0.f, 0.f, 0.f, 0.f);
    for (int r = beg + grp; r < beg + cnt; r += 8) {
        ushort4 v = *(const ushort4*)&h[(size_t)r * HC + (ct << 2)];
        acc.x += bf2f(v.x); acc.y += bf2f(v.y);
        acc.z += bf2f(v.z); acc.w += bf2f(v.w);
    }
    *(float4*)&shg[grp][ct << 2] = acc;
    __syncthreads();
    // combine the 8 partials (512 threads, one column each)
    if (tid < HC) {
        float s = shg[0][tid];
#pragma unroll
        for (int p = 1; p < 8; ++p) s += shg[p][tid];
        shg[0][tid] = s / (float)max(cnt, 1);
    }
    __syncthreads();
    if (tid < NCLS) {
        float p = bc[tid];
        for (int j = 0; j < HC; ++j) p += shg[0][j] * Wc[j * NCLS + tid];
        out[g * NCLS + tid] = p;
    }
}

// ---------------- launch ----------------
extern "C" void kernel_launch(void* const* d_in, const int* in_sizes, int n_in,
                              void* d_out, int out_size, void* d_ws, size_t ws_size,
                              hipStream_t stream) {
    const float* x     = (const float*)d_in[0];
    const int*   ei    = (const int*)d_in[1];
    const int*   batch = (const int*)d_in[2];
    const float* W1    = (const float*)d_in[3];
    const float* asrc1 = (const float*)d_in[4];
    const float* adst1 = (const float*)d_in[5];
    const float* b1    = (const float*)d_in[6];
    const float* W2    = (const float*)d_in[7];
    const float* asrc2 = (const float*)d_in[8];
    const float* adst2 = (const float*)d_in[9];
    const float* b2    = (const float*)d_in[10];
    const float* Wc    = (const float*)d_in[11];
    const float* bc    = (const float*)d_in[12];
    float* out = (float*)d_out;
    (void)in_sizes; (void)n_in; (void)out_size; (void)ws_size;

    // ---- region plan (sequential lifetimes on stream):
    // A @0      (25.6 MB): zf8 (fp8 z mirror, both layers)
    // B @25.6M  (51.2 MB): xf16 25.6 [cvt..GEMM1] -> h1f16 51.2 [gather1..GEMM2]
    //                      -> h2b 51.2 [gather2..poolcls]
    char* R = (char*)d_ws;
    const size_t MB512 = (size_t)NN * HC;        // 25.6M elements
    unsigned char* zf8 = (unsigned char*)R;
    ushort* xf16  = (ushort*)(R + MB512);
    ushort* h1f16 = (ushort*)(R + MB512);
    ushort* h2b   = (ushort*)(R + MB512);

    char* w = R + MB512 * 3;
    size_t off = 0;
    auto alloc = [&](size_t bytes) {
        void* p = w + off;
        off += (bytes + 255) & ~(size_t)255;
        return p;
    };
    float* as_b = (float*)alloc((size_t)NN * NH * 4);
    float* ad_b = (float*)alloc((size_t)NN * NH * 4);
    float* dinv = (float*)alloc((size_t)NN * NH * 4);
    int* rowptr = (int*)alloc((size_t)(NN + 1) * 4);
    int* deg    = (int*)alloc((size_t)NN * 4);
    int* fillc  = (int*)alloc((size_t)NN * 4);
    ushort* colsrc = (ushort*)alloc((size_t)NET * 2);
    int* gcnt   = (int*)alloc((size_t)NG * 4);
    int* goff   = (int*)alloc((size_t)(NG + 1) * 4);
    int* bsum   = (int*)alloc((size_t)1024 * 4);
    int* boff   = (int*)alloc((size_t)1024 * 4);
    ushort* W1T = (ushort*)alloc((size_t)HC * IND * 2);
    ushort* W2T = (ushort*)alloc((size_t)HC * HC * 2);
    ushort* alpha = (ushort*)alloc((size_t)NET * NH * 2);  // fp16, edge-major

    const int EB = 256, EG = (NET + EB - 1) / EB;
    const int MT = (NN + 63) / 64;               // 782 M-tiles (BM=64)
    const int GG = 2 * (NN >> 2);                // 2 head-pair phases
    const int NB_N = (NN + 255) / 256;

    // ---- prologue: conversions + zeroing (1 kernel) ----
    k_cvt_all<<<(CVT_TOTAL + 255) / 256, 256, 0, stream>>>(
        x, xf16, W1, W1T, W2, W2T, deg, fillc, gcnt);

    // ---- counts (fused deg + gcnt) ----
    k_count<<<(NET + NN + 255) / 256, 256, 0, stream>>>(ei, deg, batch, gcnt);

    // ---- CSR rowptr scan (+ merged graph-offset scan) ----
    k_scan_part<<<NB_N, 256, 0, stream>>>(deg, bsum, NN);
    k_scan_top<<<1, 1024, 0, stream>>>(bsum, boff, rowptr, NB_N, NN,
                                       gcnt, goff, NG);
    k_scan_out<<<NB_N, 256, 0, stream>>>(deg, boff, rowptr, NN);
    k_fill<<<EG, EB, 0, stream>>>(ei, rowptr, fillc, colsrc);

    // ================= layer 1 =================
    k_gemm_f16<<<MT * 4, 256, 0, stream>>>(xf16, W1T, asrc1, adst1,
                                           zf8, as_b, ad_b, NN, IND);
    k_stats<<<(NN + 63) / 64, 256, 0, stream>>>(as_b, ad_b, rowptr, colsrc,
                                                alpha, dinv, NN);
    k_gather<<<GG, 256, 0, stream>>>(zf8, alpha, dinv, rowptr, colsrc, b1,
                                     h1f16, 0);

    // ================= layer 2 =================
    k_gemm_f16<<<MT * 4, 256, 0, stream>>>(h1f16, W2T, asrc2, adst2,
                                           zf8, as_b, ad_b, NN, HC);
    k_stats<<<(NN + 63) / 64, 256, 0, stream>>>(as_b, ad_b, rowptr, colsrc,
                                                alpha, dinv, NN);
    k_gather<<<GG, 256, 0, stream>>>(zf8, alpha, dinv, rowptr, colsrc, b2,
                                     h2b, 1);

    // ================= pool + classify (fused, 8-way row-parallel) ========
    k_poolcls<<<NG, 1024, 0, stream>>>(h2b, goff, Wc, bc, out);
}